// Round 14
// baseline (195.120 us; speedup 1.0000x reference)
//
#include <hip/hip_runtime.h>

// ---------------------------------------------------------------------------
// MHSA bf16-MFMA pipeline v20: B=2, S=2048, D=1024, H=16, HD=64
//   p:  fused prep (z=0: W_qkv^T, z=1: W_out^T, z=2: x f32->bf16)
//   k1: qkv GEMM, tile 128x192, BK=128 (v20 change; was 64): halves the
//       per-K-step full-drain barrier pairs (m97-structure stall), LDS
//       80KB/block = exactly 2 blocks/CU; read:MFMA ratio unchanged.
//       4-bit XOR chunk swizzle (store chunk p = logical p^(row&15) via
//       pre-swizzled global src; read chunk ((kk*4+quad)^l16); 8-lane-group
//       bank rule => conflict-free, same rule as attn's measured 0).
//   k2: flash attention, v16 EXACT (verified 49.2-49.9us across 4 rounds)
//   k3: out GEMM -> f32, 128x64, BK=128 (48KB LDS)
// Frag layouts (m89/m91): x32: A[m=l16][k=quad*8+j], B[k=quad*8+j][n=l16];
// C: col=l16, row=quad*4+i.
// P redistribution (enumerated, HW-validated v8/v12/v16): with X,Y = packed
// dwords of nt=2c and Z,W of nt=2c+1 (dword = t-pair {4q+2h, 4q+2h+1}):
//   permlane32_swap(X,Z); permlane16_swap(X,Z) -> X = B-dword0, Z = B-dword2
//   same on (Y,W) -> dword1, dword3.   (B-dword j2 = t {8q+2*j2, +1})
// NOTE: v15's v_cvt_pk_bf16_f32 REVERTED permanently (absmax 13.7).
// ws (48 MB): Wout_t 0-2 | qk_bf 2-18 | vT 18-26 | attn_b 26-34 |
//             x_bf 34-42 | Wqkv_t 42-48
// ---------------------------------------------------------------------------

typedef short bf16x8 __attribute__((ext_vector_type(8)));
typedef float f32x4 __attribute__((ext_vector_type(4)));
typedef unsigned uint2v __attribute__((ext_vector_type(2)));

#define MFMA32(a, b, c) __builtin_amdgcn_mfma_f32_16x16x32_bf16(a, b, c, 0, 0, 0)

__device__ __forceinline__ unsigned short f2bf(float f) {   // RNE
  unsigned u = __float_as_uint(f);
  u = (u + 0x7fffu + ((u >> 16) & 1u)) >> 16;
  return (unsigned short)u;
}
__device__ __forceinline__ unsigned pack_bf2(float lo, float hi) {
  unsigned a = __float_as_uint(lo) + 0x8000u;
  unsigned b = __float_as_uint(hi) + 0x8000u;
  return __builtin_amdgcn_perm(b, a, 0x07060302);
}
__device__ __forceinline__ void load_lds16(const unsigned short* g, unsigned short* l) {
  __builtin_amdgcn_global_load_lds(
      (const __attribute__((address_space(1))) void*)g,
      (__attribute__((address_space(3))) void*)l, 16, 0, 0);
}

// Hazard-safe permlane swaps (gfx950), v12/v16-verified on hardware.
#if __has_builtin(__builtin_amdgcn_permlane32_swap)
__device__ __forceinline__ void pl32_swap(unsigned& a, unsigned& b) {
  uint2v r = __builtin_amdgcn_permlane32_swap(a, b, false, false);
  a = r[0]; b = r[1];
}
__device__ __forceinline__ void pl16_swap(unsigned& a, unsigned& b) {
  uint2v r = __builtin_amdgcn_permlane16_swap(a, b, false, false);
  a = r[0]; b = r[1];
}
#else
__device__ __forceinline__ void pl32_swap(unsigned& a, unsigned& b) {
  asm volatile("s_nop 1\n\tv_permlane32_swap_b32 %0, %1\n\ts_nop 1"
               : "+v"(a), "+v"(b));
}
__device__ __forceinline__ void pl16_swap(unsigned& a, unsigned& b) {
  asm volatile("s_nop 1\n\tv_permlane16_swap_b32 %0, %1\n\ts_nop 1"
               : "+v"(a), "+v"(b));
}
#endif

// --- p: fused prep ---------------------------------------------------------
__global__ __launch_bounds__(256) void prep(
    const float* __restrict__ x, unsigned short* __restrict__ x_bf,
    const float* __restrict__ W_qkv, unsigned short* __restrict__ Wqkv_t,
    const float* __restrict__ W_out, unsigned short* __restrict__ Wout_t)
{
  const int tid = threadIdx.x;
  if (blockIdx.z == 2) {
    const int bid = blockIdx.y * 48 + blockIdx.x;          // 0..767
    const int n = 4096 * 1024;
    for (int i = bid * 2048 + tid * 8; i < n; i += 768 * 2048) {
      float4 f0 = *(const float4*)(x + i);
      float4 f1 = *(const float4*)(x + i + 4);
      union { unsigned short u[8]; uint4 v; } pk;
      pk.u[0] = f2bf(f0.x); pk.u[1] = f2bf(f0.y); pk.u[2] = f2bf(f0.z); pk.u[3] = f2bf(f0.w);
      pk.u[4] = f2bf(f1.x); pk.u[5] = f2bf(f1.y); pk.u[6] = f2bf(f1.z); pk.u[7] = f2bf(f1.w);
      *(uint4*)(x_bf + i) = pk.v;
    }
    return;
  }
  const float* in = (blockIdx.z == 0) ? W_qkv : W_out;
  unsigned short* out = (blockIdx.z == 0) ? Wqkv_t : Wout_t;
  const int R = 1024;
  const int C = (blockIdx.z == 0) ? 3072 : 1024;
  const int c0 = blockIdx.x * 64;
  if (c0 >= C) return;
  __shared__ float tile[64][65];
  const int r0 = blockIdx.y * 64;
  {
    const int rr = tid >> 4;
    const int cc = (tid & 15) * 4;
#pragma unroll
    for (int it = 0; it < 4; ++it) {
      float4 f = *(const float4*)&in[(size_t)(r0 + rr + 16 * it) * C + c0 + cc];
      tile[rr + 16 * it][cc + 0] = f.x;
      tile[rr + 16 * it][cc + 1] = f.y;
      tile[rr + 16 * it][cc + 2] = f.z;
      tile[rr + 16 * it][cc + 3] = f.w;
    }
  }
  __syncthreads();
  {
    const int cr = tid >> 2;
    const int rk = (tid & 3) * 16;
    union { unsigned short u[16]; uint4 v[2]; } pk;
#pragma unroll
    for (int j = 0; j < 16; ++j) pk.u[j] = f2bf(tile[rk + j][cr]);
    uint4* dst = (uint4*)&out[(size_t)(c0 + cr) * R + r0 + rk];
    dst[0] = pk.v[0];
    dst[1] = pk.v[1];
  }
}

// --- k1/k3: GEMM C = A[M,K] @ Bt[N,K]^T + bias -----------------------------
// Tile 128 x NB (NB=192 or 64), BK=128, 4-bit XOR-swizzled LDS, XCD remap.
// MODE 0: f32 out (ldc = N). MODE 1: bf16: cols<1024 Q (scaled log2e/8),
// 1024..2047 K -> qk_bf; >=2048 V -> vT.
template <int MODE, int NB>
__global__ __launch_bounds__(256) void gemm_mfma(
    const unsigned short* __restrict__ A,
    const unsigned short* __restrict__ Bt,
    const float* __restrict__ bias,
    void* __restrict__ Cout, unsigned short* __restrict__ vT,
    int M, int N, int K, int ldc)
{
  constexpr int NI = NB / 32;              // 6 or 2
  __shared__ unsigned short As[128][128];
  __shared__ unsigned short Bs[NB][128];
  const int tid = threadIdx.x;
  const int wave = tid >> 6, lane = tid & 63;
  const int l16 = lane & 15, quad = lane >> 4;

  // XCD-aware bijective block remap (nwg % 8 == 0 for both k1 and k3)
  const int bid = blockIdx.y * gridDim.x + blockIdx.x;
  const int nwg = gridDim.x * gridDim.y;
  const int sbid = (bid & 7) * (nwg >> 3) + (bid >> 3);
  const int bx = sbid % gridDim.x;
  const int by = sbid / gridDim.x;
  const int m0 = by * 128, n0 = bx * NB;

  const int wm = (wave & 1) * 64, wn = (wave >> 1) * (NB / 2);
  // staging: lane -> row lr4 (0..3), 16B chunk p (0..15). Stored chunk p of
  // row r holds logical chunk p ^ (r&15) (pre-swizzled GLOBAL source; LDS
  // dst stays linear per m173). One call stages 4 rows (64 lanes x 16B).
  const int lr4 = lane >> 4;
  const int p16 = lane & 15;

  f32x4 acc[4][NI] = {};

  for (int k0 = 0; k0 < K; k0 += 128) {
    __syncthreads();
#pragma unroll
    for (int i = 0; i < 8; ++i) {            // A: 32 rows per wave
      const int rl = wave * 32 + i * 4 + lr4;
      load_lds16(&A[(size_t)(m0 + rl) * K + k0 + ((p16 ^ (rl & 15)) << 3)],
                 &As[wave * 32 + i * 4][0]);
    }
#pragma unroll
    for (int i = 0; i < NB / 16; ++i) {      // B: NB/4 rows per wave
      const int rl = wave * (NB / 4) + i * 4 + lr4;
      load_lds16(&Bt[(size_t)(n0 + rl) * K + k0 + ((p16 ^ (rl & 15)) << 3)],
                 &Bs[wave * (NB / 4) + i * 4][0]);
    }
    __syncthreads();

#pragma unroll
    for (int kk = 0; kk < 4; ++kk) {
      bf16x8 af[4], bfr[NI];
#pragma unroll
      for (int mi = 0; mi < 4; ++mi)
        af[mi] = *(const bf16x8*)&As[wm + 16 * mi + l16][(((kk << 2) + quad) ^ l16) * 8];
#pragma unroll
      for (int ni = 0; ni < NI; ++ni)
        bfr[ni] = *(const bf16x8*)&Bs[wn + 16 * ni + l16][(((kk << 2) + quad) ^ l16) * 8];
#pragma unroll
      for (int mi = 0; mi < 4; ++mi)
#pragma unroll
        for (int ni = 0; ni < NI; ++ni)
          acc[mi][ni] = __builtin_amdgcn_mfma_f32_16x16x32_bf16(
              af[mi], bfr[ni], acc[mi][ni], 0, 0, 0);
    }
  }

  const float SCQ = 0.18033688f;   // log2(e)/sqrt(64), folded into Q
#pragma unroll
  for (int ni = 0; ni < NI; ++ni) {
    const int colb = n0 + wn + 16 * ni;
    const int col = colb + l16;
    const float bv = bias[col];
    if (MODE == 0) {
#pragma unroll
      for (int mi = 0; mi < 4; ++mi)
#pragma unroll
        for (int i = 0; i < 4; ++i) {
          const int row = m0 + wm + 16 * mi + quad * 4 + i;
          ((float*)Cout)[(size_t)row * ldc + col] = acc[mi][ni][i] + bv;
        }
    } else if (colb < 1024) {          // Q: pre-scale for exp2 softmax
#pragma unroll
      for (int mi = 0; mi < 4; ++mi)
#pragma unroll
        for (int i = 0; i < 4; ++i) {
          const int row = m0 + wm + 16 * mi + quad * 4 + i;
          ((unsigned short*)Cout)[(size_t)row * ldc + col] = f2bf((acc[mi][ni][i] + bv) * SCQ);
        }
    } else if (colb < 2048) {          // K
#pragma unroll
      for (int mi = 0; mi < 4; ++mi)
#pragma unroll
        for (int i = 0; i < 4; ++i) {
          const int row = m0 + wm + 16 * mi + quad * 4 + i;
          ((unsigned short*)Cout)[(size_t)row * ldc + col] = f2bf(acc[mi][ni][i] + bv);
        }
    } else {                           // V -> vT[bh][d][t], packed pairs in t
      const int h = (col - 2048) >> 6, d = col & 63;
#pragma unroll
      for (int mi = 0; mi < 4; ++mi) {
        const int row = m0 + wm + 16 * mi + quad * 4;   // +i, i=0..3
        const int bb = row >> 11, t = row & 2047;
        unsigned short* dst = &vT[((size_t)(bb * 16 + h) * 64 + d) * 2048 + t];
        *(unsigned*)(dst)     = pack_bf2(acc[mi][ni][0] + bv, acc[mi][ni][1] + bv);
        *(unsigned*)(dst + 2) = pack_bf2(acc[mi][ni][2] + bv, acc[mi][ni][3] + bv);
      }
    }
  }
}

// --- k2: flash attention, v16 EXACT (verified 49.2-49.9 us) ----------------
// Block = 4 waves; wave w: q rows [bx*128 + 32w, +32), all 2048 keys.
// K,V tiles (64x64 bf16) double-buffered in LDS; staging goes global->VGPR
// (issued one iter ahead) -> ds_write; per-iter barrier. XOR chunk swizzle
// (chunk c of row r at c ^ (r&7)). S^T = K Q^T (x32); P -> x32 B-frags via
// pack_bf2 + permlane swaps; PV and l via x32 MFMA.
__global__ __launch_bounds__(256, 2) void attn_mfma(
    const unsigned short* __restrict__ qk,    // [4096][2048] (Q|K)
    const unsigned short* __restrict__ vT,    // [32][64][2048]
    unsigned short* __restrict__ attn_out)    // [4096][1024]
{
  __shared__ unsigned short Ks[2][4096];
  __shared__ unsigned short Vs[2][4096];

  const int tid = threadIdx.x;
  const int wave = tid >> 6, lane = tid & 63;
  const int l16 = lane & 15, quad = lane >> 4;
  const int bh = blockIdx.y, b = bh >> 4, h = bh & 15;
  const int s0 = blockIdx.x * 128 + wave * 32;

  const unsigned short* qb = qk + (size_t)(b * 2048) * 2048 + h * 64;
  const unsigned short* kb = qb + 1024;
  const unsigned short* vb = vT + (size_t)bh * 64 * 2048;

  // staging geometry (16B per lane, swizzled chunks)
  const int srow = lane >> 3;                     // 0..7
  const int schunk = ((lane & 7) ^ srow) * 8;     // swizzled 16B chunk
  const int r0a = wave * 16;
  const unsigned short* kg0 = kb + (size_t)(r0a + srow) * 2048 + schunk;
  const unsigned short* kg1 = kg0 + (size_t)8 * 2048;
  const unsigned short* vg0 = vb + (size_t)(r0a + srow) * 2048 + schunk;
  const unsigned short* vg1 = vg0 + (size_t)8 * 2048;
  const int wd0 = r0a * 64 + lane * 8;            // LDS dst (shorts)
  const int wd1 = (r0a + 8) * 64 + lane * 8;

  // tile 0 -> buf 0; tile 1 into regs (in flight across first compute)
  uint4 kr0 = *(const uint4*)(kg0);
  uint4 kr1 = *(const uint4*)(kg1);
  uint4 vr0 = *(const uint4*)(vg0);
  uint4 vr1 = *(const uint4*)(vg1);
  *(uint4*)&Ks[0][wd0] = kr0;  *(uint4*)&Ks[0][wd1] = kr1;
  *(uint4*)&Vs[0][wd0] = vr0;  *(uint4*)&Vs[0][wd1] = vr1;
  kr0 = *(const uint4*)(kg0 + (size_t)64 * 2048);
  kr1 = *(const uint4*)(kg1 + (size_t)64 * 2048);
  vr0 = *(const uint4*)(vg0 + 64);
  vr1 = *(const uint4*)(vg1 + 64);

  // Q frags (x32 B-layout: k=d, n=q); Q pre-scaled by log2e/8
  bf16x8 qf[2][2];
#pragma unroll
  for (int mt = 0; mt < 2; ++mt)
#pragma unroll
    for (int ks = 0; ks < 2; ++ks)
      qf[mt][ks] = *(const bf16x8*)&qb[(size_t)(s0 + 16 * mt + l16) * 2048 + 32 * ks + quad * 8];

  f32x4 O[2][4] = {};      // O^T accum: [mt][nd], C col=q=l16, row=d local
  f32x4 lacc[2] = {};      // l via ones-MFMA (rows replicated)
  const bf16x8 ones8 = {(short)0x3F80, (short)0x3F80, (short)0x3F80, (short)0x3F80,
                        (short)0x3F80, (short)0x3F80, (short)0x3F80, (short)0x3F80};
  const int sw = l16 & 7;

  __syncthreads();

  for (int it = 0; it < 32; ++it) {
    const int cur = it & 1;

    // ---- K frags (x32 A-layout: m=t, k=d) from swizzled LDS ----
    bf16x8 kf[4][2];
#pragma unroll
    for (int nt = 0; nt < 4; ++nt) {
      const int rb = (16 * nt + l16) * 64;
      kf[nt][0] = *(const bf16x8*)&Ks[cur][rb + ((quad ^ sw) * 8)];
      kf[nt][1] = *(const bf16x8*)&Ks[cur][rb + (((4 + quad) ^ sw) * 8)];
    }

    // ---- S^T = K Q^T (x32): C row=t=quad*4+i, col=q=l16 ----
    f32x4 sf[4][2];
#pragma unroll
    for (int nt = 0; nt < 4; ++nt)
#pragma unroll
      for (int mt = 0; mt < 2; ++mt) {
        f32x4 c = {0.0f, 0.0f, 0.0f, 0.0f};
        c = __builtin_amdgcn_mfma_f32_16x16x32_bf16(kf[nt][0], qf[mt][0], c, 0, 0, 0);
        c = __builtin_amdgcn_mfma_f32_16x16x32_bf16(kf[nt][1], qf[mt][1], c, 0, 0, 0);
        sf[nt][mt] = c;
      }

    // ---- stage tile it+1 (regs -> other buffer); prefetch tile it+2 ----
    if (it < 31) {
      *(uint4*)&Ks[cur ^ 1][wd0] = kr0;
      *(uint4*)&Ks[cur ^ 1][wd1] = kr1;
      *(uint4*)&Vs[cur ^ 1][wd0] = vr0;
      *(uint4*)&Vs[cur ^ 1][wd1] = vr1;
      if (it < 30) {
        const size_t ko = (size_t)(it + 2) * 64 * 2048;
        kr0 = *(const uint4*)(kg0 + ko);
        kr1 = *(const uint4*)(kg1 + ko);
        vr0 = *(const uint4*)(vg0 + (it + 2) * 64);
        vr1 = *(const uint4*)(vg1 + (it + 2) * 64);
      }
    }

    // ---- V frags (x32 A-layout: m=d, k=t): same swizzle as K ----
    bf16x8 vf[4][2];
#pragma unroll
    for (int nd = 0; nd < 4; ++nd) {
      const int rb = (16 * nd + l16) * 64;
      vf[nd][0] = *(const bf16x8*)&Vs[cur][rb + ((quad ^ sw) * 8)];
      vf[nd][1] = *(const bf16x8*)&Vs[cur][rb + (((4 + quad) ^ sw) * 8)];
    }

    // ---- p = exp2(s); pack_bf2; permlane-redistribute to x32 B-frags ----
    bf16x8 pB[2][2];   // [mt][c]
#pragma unroll
    for (int mt = 0; mt < 2; ++mt)
#pragma unroll
      for (int c = 0; c < 2; ++c) {
        const f32x4 sa = sf[2 * c][mt];
        const f32x4 sb = sf[2 * c + 1][mt];
        unsigned X = pack_bf2(__builtin_amdgcn_exp2f(sa[0]), __builtin_amdgcn_exp2f(sa[1]));
        unsigned Y = pack_bf2(__builtin_amdgcn_exp2f(sa[2]), __builtin_amdgcn_exp2f(sa[3]));
        unsigned Z = pack_bf2(__builtin_amdgcn_exp2f(sb[0]), __builtin_amdgcn_exp2f(sb[1]));
        unsigned W = pack_bf2(__builtin_amdgcn_exp2f(sb[2]), __builtin_amdgcn_exp2f(sb[3]));
        pl32_swap(X, Z);
        pl16_swap(X, Z);
        pl32_swap(Y, W);
        pl16_swap(Y, W);
        union { unsigned u[4]; bf16x8 v; } pk;
        pk.u[0] = X; pk.u[1] = Y; pk.u[2] = Z; pk.u[3] = W;
        pB[mt][c] = pk.v;
      }

    // ---- O^T += V^T P^T (x32); l += ones P^T (x32) ----
#pragma unroll
    for (int c = 0; c < 2; ++c)
#pragma unroll
      for (int mt = 0; mt < 2; ++mt) {
        lacc[mt] = MFMA32(ones8, pB[mt][c], lacc[mt]);
#pragma unroll
        for (int nd = 0; nd < 4; ++nd)
          O[mt][nd] = MFMA32(vf[nd][c], pB[mt][c], O[mt][nd]);
      }

    __syncthreads();
  }

  // ---- epilogue: lane holds q=s0+16mt+l16, d=16nd+quad*4+{0..3} ----
#pragma unroll
  for (int mt = 0; mt < 2; ++mt) {
    const float inv = 1.0f / lacc[mt][0];
    const size_t row = (size_t)(b * 2048 + s0 + 16 * mt + l16);
#pragma unroll
    for (int nd = 0; nd < 4; ++nd) {
      uint2 w;
      w.x = pack_bf2(O[mt][nd][0] * inv, O[mt][nd][1] * inv);
      w.y = pack_bf2(O[mt][nd][2] * inv, O[mt][nd][3] * inv);
      *(uint2*)&attn_out[row * 1024 + h * 64 + 16 * nd + quad * 4] = w;
    }
  }
}

extern "C" void kernel_launch(void* const* d_in, const int* in_sizes, int n_in,
                              void* d_out, int out_size, void* d_ws, size_t ws_size,
                              hipStream_t stream) {
  const float* x     = (const float*)d_in[0];
  const float* W_qkv = (const float*)d_in[1];
  const float* b_qkv = (const float*)d_in[2];
  const float* W_out = (const float*)d_in[3];
  const float* b_out = (const float*)d_in[4];
  float* out = (float*)d_out;

  char* ws = (char*)d_ws;
  const size_t MB = 1048576;
  unsigned short* Wout_t = (unsigned short*)(ws);             //  0-2 MB
  unsigned short* qk_bf  = (unsigned short*)(ws + 2 * MB);    //  2-18 MB
  unsigned short* vT     = (unsigned short*)(ws + 18 * MB);   // 18-26 MB
  unsigned short* attn_b = (unsigned short*)(ws + 26 * MB);   // 26-34 MB
  unsigned short* x_bf   = (unsigned short*)(ws + 34 * MB);   // 34-42 MB
  unsigned short* Wqkv_t = (unsigned short*)(ws + 42 * MB);   // 42-48 MB

  prep<<<dim3(48, 16, 3), 256, 0, stream>>>(x, x_bf, W_qkv, Wqkv_t, W_out, Wout_t);

  gemm_mfma<1, 192><<<dim3(16, 32), 256, 0, stream>>>(x_bf, Wqkv_t, b_qkv, qk_bf, vT,
                                                      4096, 3072, 1024, 2048);
  attn_mfma<<<dim3(16, 32), 256, 0, stream>>>(qk_bf, vT, attn_b);
  gemm_mfma<0, 64><<<dim3(16, 32), 256, 0, stream>>>(attn_b, Wout_t, b_out, out, nullptr,
                                                     4096, 1024, 1024, 1024);
}

// Round 15
// 182.246 us; speedup vs baseline: 1.0706x; 1.0706x over previous
//
#include <hip/hip_runtime.h>

// ---------------------------------------------------------------------------
// MHSA bf16-MFMA pipeline v21: B=2, S=2048, D=1024, H=16, HD=64
//   p:  fused prep (z=0: W_qkv^T, z=1: W_out^T, z=2: x f32->bf16)
//   k1: qkv GEMM, tile 128x192, BK=64, 40KB LDS (v19-verified, best: 179.6)
//   k3: out GEMM -> f32, 128x64, BK=128, 48KB LDS (v21 change: barrier
//       halving WITHOUT the v20 occupancy cliff -- v20's k1@80KB LDS gave
//       1 block/CU (occ 10%, 54us); rule: GEMM LDS <= 64KB for 2 blocks/CU)
//   k2: flash attention, v16 EXACT (verified 49.2-49.9us across 5 rounds)
// GEMM template generic over BK: CPR=BK/8 chunks/row; store chunk p of row
// r holds logical p^(r&(CPR-1)) via pre-swizzled global src (LDS dst linear
// per m173); read chunk (kk*4+quad)^(l16&(CPR-1)). Reproduces v19 (BK=64)
// and v20 (BK=128) swizzles exactly; 2-way bank alias only (free, m136).
// Frag layouts (m89/m91): x32: A[m=l16][k=quad*8+j], B[k=quad*8+j][n=l16];
// C: col=l16, row=quad*4+i.
// P redistribution (HW-validated v8/v12/v16): permlane32+16 swap pairs.
// NOTE: v15's v_cvt_pk_bf16_f32 REVERTED permanently (absmax 13.7).
// ws (48 MB): Wout_t 0-2 | qk_bf 2-18 | vT 18-26 | attn_b 26-34 |
//             x_bf 34-42 | Wqkv_t 42-48
// ---------------------------------------------------------------------------

typedef short bf16x8 __attribute__((ext_vector_type(8)));
typedef float f32x4 __attribute__((ext_vector_type(4)));
typedef unsigned uint2v __attribute__((ext_vector_type(2)));

#define MFMA32(a, b, c) __builtin_amdgcn_mfma_f32_16x16x32_bf16(a, b, c, 0, 0, 0)

__device__ __forceinline__ unsigned short f2bf(float f) {   // RNE
  unsigned u = __float_as_uint(f);
  u = (u + 0x7fffu + ((u >> 16) & 1u)) >> 16;
  return (unsigned short)u;
}
__device__ __forceinline__ unsigned pack_bf2(float lo, float hi) {
  unsigned a = __float_as_uint(lo) + 0x8000u;
  unsigned b = __float_as_uint(hi) + 0x8000u;
  return __builtin_amdgcn_perm(b, a, 0x07060302);
}
__device__ __forceinline__ void load_lds16(const unsigned short* g, unsigned short* l) {
  __builtin_amdgcn_global_load_lds(
      (const __attribute__((address_space(1))) void*)g,
      (__attribute__((address_space(3))) void*)l, 16, 0, 0);
}

// Hazard-safe permlane swaps (gfx950), v12/v16-verified on hardware.
#if __has_builtin(__builtin_amdgcn_permlane32_swap)
__device__ __forceinline__ void pl32_swap(unsigned& a, unsigned& b) {
  uint2v r = __builtin_amdgcn_permlane32_swap(a, b, false, false);
  a = r[0]; b = r[1];
}
__device__ __forceinline__ void pl16_swap(unsigned& a, unsigned& b) {
  uint2v r = __builtin_amdgcn_permlane16_swap(a, b, false, false);
  a = r[0]; b = r[1];
}
#else
__device__ __forceinline__ void pl32_swap(unsigned& a, unsigned& b) {
  asm volatile("s_nop 1\n\tv_permlane32_swap_b32 %0, %1\n\ts_nop 1"
               : "+v"(a), "+v"(b));
}
__device__ __forceinline__ void pl16_swap(unsigned& a, unsigned& b) {
  asm volatile("s_nop 1\n\tv_permlane16_swap_b32 %0, %1\n\ts_nop 1"
               : "+v"(a), "+v"(b));
}
#endif

// --- p: fused prep ---------------------------------------------------------
__global__ __launch_bounds__(256) void prep(
    const float* __restrict__ x, unsigned short* __restrict__ x_bf,
    const float* __restrict__ W_qkv, unsigned short* __restrict__ Wqkv_t,
    const float* __restrict__ W_out, unsigned short* __restrict__ Wout_t)
{
  const int tid = threadIdx.x;
  if (blockIdx.z == 2) {
    const int bid = blockIdx.y * 48 + blockIdx.x;          // 0..767
    const int n = 4096 * 1024;
    for (int i = bid * 2048 + tid * 8; i < n; i += 768 * 2048) {
      float4 f0 = *(const float4*)(x + i);
      float4 f1 = *(const float4*)(x + i + 4);
      union { unsigned short u[8]; uint4 v; } pk;
      pk.u[0] = f2bf(f0.x); pk.u[1] = f2bf(f0.y); pk.u[2] = f2bf(f0.z); pk.u[3] = f2bf(f0.w);
      pk.u[4] = f2bf(f1.x); pk.u[5] = f2bf(f1.y); pk.u[6] = f2bf(f1.z); pk.u[7] = f2bf(f1.w);
      *(uint4*)(x_bf + i) = pk.v;
    }
    return;
  }
  const float* in = (blockIdx.z == 0) ? W_qkv : W_out;
  unsigned short* out = (blockIdx.z == 0) ? Wqkv_t : Wout_t;
  const int R = 1024;
  const int C = (blockIdx.z == 0) ? 3072 : 1024;
  const int c0 = blockIdx.x * 64;
  if (c0 >= C) return;
  __shared__ float tile[64][65];
  const int r0 = blockIdx.y * 64;
  {
    const int rr = tid >> 4;
    const int cc = (tid & 15) * 4;
#pragma unroll
    for (int it = 0; it < 4; ++it) {
      float4 f = *(const float4*)&in[(size_t)(r0 + rr + 16 * it) * C + c0 + cc];
      tile[rr + 16 * it][cc + 0] = f.x;
      tile[rr + 16 * it][cc + 1] = f.y;
      tile[rr + 16 * it][cc + 2] = f.z;
      tile[rr + 16 * it][cc + 3] = f.w;
    }
  }
  __syncthreads();
  {
    const int cr = tid >> 2;
    const int rk = (tid & 3) * 16;
    union { unsigned short u[16]; uint4 v[2]; } pk;
#pragma unroll
    for (int j = 0; j < 16; ++j) pk.u[j] = f2bf(tile[rk + j][cr]);
    uint4* dst = (uint4*)&out[(size_t)(c0 + cr) * R + r0 + rk];
    dst[0] = pk.v[0];
    dst[1] = pk.v[1];
  }
}

// --- k1/k3: GEMM C = A[M,K] @ Bt[N,K]^T + bias -----------------------------
// Tile 128 x NB, K-step BK. XOR-swizzled LDS (CPR=BK/8 chunks/row), XCD
// remap. MODE 0: f32 out (ldc = N). MODE 1: bf16: cols<1024 Q (scaled
// log2e/8), 1024..2047 K -> qk_bf; >=2048 V -> vT.
template <int MODE, int NB, int BK>
__global__ __launch_bounds__(256) void gemm_mfma(
    const unsigned short* __restrict__ A,
    const unsigned short* __restrict__ Bt,
    const float* __restrict__ bias,
    void* __restrict__ Cout, unsigned short* __restrict__ vT,
    int M, int N, int K, int ldc)
{
  constexpr int NI = NB / 32;
  constexpr int CPR = BK / 8;              // 16B chunks per row
  constexpr int RPC = 64 / CPR;            // rows staged per load call
  __shared__ unsigned short As[128][BK];
  __shared__ unsigned short Bs[NB][BK];
  const int tid = threadIdx.x;
  const int wave = tid >> 6, lane = tid & 63;
  const int l16 = lane & 15, quad = lane >> 4;

  // XCD-aware bijective block remap (nwg % 8 == 0 for both k1 and k3)
  const int bid = blockIdx.y * gridDim.x + blockIdx.x;
  const int nwg = gridDim.x * gridDim.y;
  const int sbid = (bid & 7) * (nwg >> 3) + (bid >> 3);
  const int bx = sbid % gridDim.x;
  const int by = sbid / gridDim.x;
  const int m0 = by * 128, n0 = bx * NB;

  const int wm = (wave & 1) * 64, wn = (wave >> 1) * (NB / 2);
  // staging: lane -> row lr (0..RPC-1), chunk p (0..CPR-1); stored chunk p
  // of row r holds logical p^(r&(CPR-1)) via pre-swizzled GLOBAL source
  // (LDS dst linear per m173)
  const int lr = lane / CPR;
  const int p  = lane % CPR;
  const int swk = l16 & (CPR - 1);         // read-side swizzle key

  f32x4 acc[4][NI] = {};

  for (int k0 = 0; k0 < K; k0 += BK) {
    __syncthreads();
#pragma unroll
    for (int i = 0; i < 32 / RPC; ++i) {   // A: 32 rows per wave
      const int rbase = wave * 32 + i * RPC;
      const int rl = rbase + lr;
      load_lds16(&A[(size_t)(m0 + rl) * K + k0 + ((p ^ (rl & (CPR - 1))) << 3)],
                 &As[rbase][0]);
    }
#pragma unroll
    for (int i = 0; i < (NB / 4) / RPC; ++i) {  // B: NB/4 rows per wave
      const int rbase = wave * (NB / 4) + i * RPC;
      const int rl = rbase + lr;
      load_lds16(&Bt[(size_t)(n0 + rl) * K + k0 + ((p ^ (rl & (CPR - 1))) << 3)],
                 &Bs[rbase][0]);
    }
    __syncthreads();

#pragma unroll
    for (int kk = 0; kk < BK / 32; ++kk) {
      bf16x8 af[4], bfr[NI];
#pragma unroll
      for (int mi = 0; mi < 4; ++mi)
        af[mi] = *(const bf16x8*)&As[wm + 16 * mi + l16][(((kk << 2) + quad) ^ swk) * 8];
#pragma unroll
      for (int ni = 0; ni < NI; ++ni)
        bfr[ni] = *(const bf16x8*)&Bs[wn + 16 * ni + l16][(((kk << 2) + quad) ^ swk) * 8];
#pragma unroll
      for (int mi = 0; mi < 4; ++mi)
#pragma unroll
        for (int ni = 0; ni < NI; ++ni)
          acc[mi][ni] = __builtin_amdgcn_mfma_f32_16x16x32_bf16(
              af[mi], bfr[ni], acc[mi][ni], 0, 0, 0);
    }
  }

  const float SCQ = 0.18033688f;   // log2(e)/sqrt(64), folded into Q
#pragma unroll
  for (int ni = 0; ni < NI; ++ni) {
    const int colb = n0 + wn + 16 * ni;
    const int col = colb + l16;
    const float bv = bias[col];
    if (MODE == 0) {
#pragma unroll
      for (int mi = 0; mi < 4; ++mi)
#pragma unroll
        for (int i = 0; i < 4; ++i) {
          const int row = m0 + wm + 16 * mi + quad * 4 + i;
          ((float*)Cout)[(size_t)row * ldc + col] = acc[mi][ni][i] + bv;
        }
    } else if (colb < 1024) {          // Q: pre-scale for exp2 softmax
#pragma unroll
      for (int mi = 0; mi < 4; ++mi)
#pragma unroll
        for (int i = 0; i < 4; ++i) {
          const int row = m0 + wm + 16 * mi + quad * 4 + i;
          ((unsigned short*)Cout)[(size_t)row * ldc + col] = f2bf((acc[mi][ni][i] + bv) * SCQ);
        }
    } else if (colb < 2048) {          // K
#pragma unroll
      for (int mi = 0; mi < 4; ++mi)
#pragma unroll
        for (int i = 0; i < 4; ++i) {
          const int row = m0 + wm + 16 * mi + quad * 4 + i;
          ((unsigned short*)Cout)[(size_t)row * ldc + col] = f2bf(acc[mi][ni][i] + bv);
        }
    } else {                           // V -> vT[bh][d][t], packed pairs in t
      const int h = (col - 2048) >> 6, d = col & 63;
#pragma unroll
      for (int mi = 0; mi < 4; ++mi) {
        const int row = m0 + wm + 16 * mi + quad * 4;   // +i, i=0..3
        const int bb = row >> 11, t = row & 2047;
        unsigned short* dst = &vT[((size_t)(bb * 16 + h) * 64 + d) * 2048 + t];
        *(unsigned*)(dst)     = pack_bf2(acc[mi][ni][0] + bv, acc[mi][ni][1] + bv);
        *(unsigned*)(dst + 2) = pack_bf2(acc[mi][ni][2] + bv, acc[mi][ni][3] + bv);
      }
    }
  }
}

// --- k2: flash attention, v16 EXACT (verified 49.2-49.9 us) ----------------
// Block = 4 waves; wave w: q rows [bx*128 + 32w, +32), all 2048 keys.
// K,V tiles (64x64 bf16) double-buffered in LDS; staging goes global->VGPR
// (issued one iter ahead) -> ds_write; per-iter barrier. XOR chunk swizzle
// (chunk c of row r at c ^ (r&7)). S^T = K Q^T (x32); P -> x32 B-frags via
// pack_bf2 + permlane swaps; PV and l via x32 MFMA.
__global__ __launch_bounds__(256, 2) void attn_mfma(
    const unsigned short* __restrict__ qk,    // [4096][2048] (Q|K)
    const unsigned short* __restrict__ vT,    // [32][64][2048]
    unsigned short* __restrict__ attn_out)    // [4096][1024]
{
  __shared__ unsigned short Ks[2][4096];
  __shared__ unsigned short Vs[2][4096];

  const int tid = threadIdx.x;
  const int wave = tid >> 6, lane = tid & 63;
  const int l16 = lane & 15, quad = lane >> 4;
  const int bh = blockIdx.y, b = bh >> 4, h = bh & 15;
  const int s0 = blockIdx.x * 128 + wave * 32;

  const unsigned short* qb = qk + (size_t)(b * 2048) * 2048 + h * 64;
  const unsigned short* kb = qb + 1024;
  const unsigned short* vb = vT + (size_t)bh * 64 * 2048;

  // staging geometry (16B per lane, swizzled chunks)
  const int srow = lane >> 3;                     // 0..7
  const int schunk = ((lane & 7) ^ srow) * 8;     // swizzled 16B chunk
  const int r0a = wave * 16;
  const unsigned short* kg0 = kb + (size_t)(r0a + srow) * 2048 + schunk;
  const unsigned short* kg1 = kg0 + (size_t)8 * 2048;
  const unsigned short* vg0 = vb + (size_t)(r0a + srow) * 2048 + schunk;
  const unsigned short* vg1 = vg0 + (size_t)8 * 2048;
  const int wd0 = r0a * 64 + lane * 8;            // LDS dst (shorts)
  const int wd1 = (r0a + 8) * 64 + lane * 8;

  // tile 0 -> buf 0; tile 1 into regs (in flight across first compute)
  uint4 kr0 = *(const uint4*)(kg0);
  uint4 kr1 = *(const uint4*)(kg1);
  uint4 vr0 = *(const uint4*)(vg0);
  uint4 vr1 = *(const uint4*)(vg1);
  *(uint4*)&Ks[0][wd0] = kr0;  *(uint4*)&Ks[0][wd1] = kr1;
  *(uint4*)&Vs[0][wd0] = vr0;  *(uint4*)&Vs[0][wd1] = vr1;
  kr0 = *(const uint4*)(kg0 + (size_t)64 * 2048);
  kr1 = *(const uint4*)(kg1 + (size_t)64 * 2048);
  vr0 = *(const uint4*)(vg0 + 64);
  vr1 = *(const uint4*)(vg1 + 64);

  // Q frags (x32 B-layout: k=d, n=q); Q pre-scaled by log2e/8
  bf16x8 qf[2][2];
#pragma unroll
  for (int mt = 0; mt < 2; ++mt)
#pragma unroll
    for (int ks = 0; ks < 2; ++ks)
      qf[mt][ks] = *(const bf16x8*)&qb[(size_t)(s0 + 16 * mt + l16) * 2048 + 32 * ks + quad * 8];

  f32x4 O[2][4] = {};      // O^T accum: [mt][nd], C col=q=l16, row=d local
  f32x4 lacc[2] = {};      // l via ones-MFMA (rows replicated)
  const bf16x8 ones8 = {(short)0x3F80, (short)0x3F80, (short)0x3F80, (short)0x3F80,
                        (short)0x3F80, (short)0x3F80, (short)0x3F80, (short)0x3F80};
  const int sw = l16 & 7;

  __syncthreads();

  for (int it = 0; it < 32; ++it) {
    const int cur = it & 1;

    // ---- K frags (x32 A-layout: m=t, k=d) from swizzled LDS ----
    bf16x8 kf[4][2];
#pragma unroll
    for (int nt = 0; nt < 4; ++nt) {
      const int rb = (16 * nt + l16) * 64;
      kf[nt][0] = *(const bf16x8*)&Ks[cur][rb + ((quad ^ sw) * 8)];
      kf[nt][1] = *(const bf16x8*)&Ks[cur][rb + (((4 + quad) ^ sw) * 8)];
    }

    // ---- S^T = K Q^T (x32): C row=t=quad*4+i, col=q=l16 ----
    f32x4 sf[4][2];
#pragma unroll
    for (int nt = 0; nt < 4; ++nt)
#pragma unroll
      for (int mt = 0; mt < 2; ++mt) {
        f32x4 c = {0.0f, 0.0f, 0.0f, 0.0f};
        c = __builtin_amdgcn_mfma_f32_16x16x32_bf16(kf[nt][0], qf[mt][0], c, 0, 0, 0);
        c = __builtin_amdgcn_mfma_f32_16x16x32_bf16(kf[nt][1], qf[mt][1], c, 0, 0, 0);
        sf[nt][mt] = c;
      }

    // ---- stage tile it+1 (regs -> other buffer); prefetch tile it+2 ----
    if (it < 31) {
      *(uint4*)&Ks[cur ^ 1][wd0] = kr0;
      *(uint4*)&Ks[cur ^ 1][wd1] = kr1;
      *(uint4*)&Vs[cur ^ 1][wd0] = vr0;
      *(uint4*)&Vs[cur ^ 1][wd1] = vr1;
      if (it < 30) {
        const size_t ko = (size_t)(it + 2) * 64 * 2048;
        kr0 = *(const uint4*)(kg0 + ko);
        kr1 = *(const uint4*)(kg1 + ko);
        vr0 = *(const uint4*)(vg0 + (it + 2) * 64);
        vr1 = *(const uint4*)(vg1 + (it + 2) * 64);
      }
    }

    // ---- V frags (x32 A-layout: m=d, k=t): same swizzle as K ----
    bf16x8 vf[4][2];
#pragma unroll
    for (int nd = 0; nd < 4; ++nd) {
      const int rb = (16 * nd + l16) * 64;
      vf[nd][0] = *(const bf16x8*)&Vs[cur][rb + ((quad ^ sw) * 8)];
      vf[nd][1] = *(const bf16x8*)&Vs[cur][rb + (((4 + quad) ^ sw) * 8)];
    }

    // ---- p = exp2(s); pack_bf2; permlane-redistribute to x32 B-frags ----
    bf16x8 pB[2][2];   // [mt][c]
#pragma unroll
    for (int mt = 0; mt < 2; ++mt)
#pragma unroll
      for (int c = 0; c < 2; ++c) {
        const f32x4 sa = sf[2 * c][mt];
        const f32x4 sb = sf[2 * c + 1][mt];
        unsigned X = pack_bf2(__builtin_amdgcn_exp2f(sa[0]), __builtin_amdgcn_exp2f(sa[1]));
        unsigned Y = pack_bf2(__builtin_amdgcn_exp2f(sa[2]), __builtin_amdgcn_exp2f(sa[3]));
        unsigned Z = pack_bf2(__builtin_amdgcn_exp2f(sb[0]), __builtin_amdgcn_exp2f(sb[1]));
        unsigned W = pack_bf2(__builtin_amdgcn_exp2f(sb[2]), __builtin_amdgcn_exp2f(sb[3]));
        pl32_swap(X, Z);
        pl16_swap(X, Z);
        pl32_swap(Y, W);
        pl16_swap(Y, W);
        union { unsigned u[4]; bf16x8 v; } pk;
        pk.u[0] = X; pk.u[1] = Y; pk.u[2] = Z; pk.u[3] = W;
        pB[mt][c] = pk.v;
      }

    // ---- O^T += V^T P^T (x32); l += ones P^T (x32) ----
#pragma unroll
    for (int c = 0; c < 2; ++c)
#pragma unroll
      for (int mt = 0; mt < 2; ++mt) {
        lacc[mt] = MFMA32(ones8, pB[mt][c], lacc[mt]);
#pragma unroll
        for (int nd = 0; nd < 4; ++nd)
          O[mt][nd] = MFMA32(vf[nd][c], pB[mt][c], O[mt][nd]);
      }

    __syncthreads();
  }

  // ---- epilogue: lane holds q=s0+16mt+l16, d=16nd+quad*4+{0..3} ----
#pragma unroll
  for (int mt = 0; mt < 2; ++mt) {
    const float inv = 1.0f / lacc[mt][0];
    const size_t row = (size_t)(b * 2048 + s0 + 16 * mt + l16);
#pragma unroll
    for (int nd = 0; nd < 4; ++nd) {
      uint2 w;
      w.x = pack_bf2(O[mt][nd][0] * inv, O[mt][nd][1] * inv);
      w.y = pack_bf2(O[mt][nd][2] * inv, O[mt][nd][3] * inv);
      *(uint2*)&attn_out[row * 1024 + h * 64 + 16 * nd + quad * 4] = w;
    }
  }
}

extern "C" void kernel_launch(void* const* d_in, const int* in_sizes, int n_in,
                              void* d_out, int out_size, void* d_ws, size_t ws_size,
                              hipStream_t stream) {
  const float* x     = (const float*)d_in[0];
  const float* W_qkv = (const float*)d_in[1];
  const float* b_qkv = (const float*)d_in[2];
  const float* W_out = (const float*)d_in[3];
  const float* b_out = (const float*)d_in[4];
  float* out = (float*)d_out;

  char* ws = (char*)d_ws;
  const size_t MB = 1048576;
  unsigned short* Wout_t = (unsigned short*)(ws);             //  0-2 MB
  unsigned short* qk_bf  = (unsigned short*)(ws + 2 * MB);    //  2-18 MB
  unsigned short* vT     = (unsigned short*)(ws + 18 * MB);   // 18-26 MB
  unsigned short* attn_b = (unsigned short*)(ws + 26 * MB);   // 26-34 MB
  unsigned short* x_bf   = (unsigned short*)(ws + 34 * MB);   // 34-42 MB
  unsigned short* Wqkv_t = (unsigned short*)(ws + 42 * MB);   // 42-48 MB

  prep<<<dim3(48, 16, 3), 256, 0, stream>>>(x, x_bf, W_qkv, Wqkv_t, W_out, Wout_t);

  gemm_mfma<1, 192, 64><<<dim3(16, 32), 256, 0, stream>>>(x_bf, Wqkv_t, b_qkv, qk_bf, vT,
                                                          4096, 3072, 1024, 2048);
  attn_mfma<<<dim3(16, 32), 256, 0, stream>>>(qk_bf, vT, attn_b);
  gemm_mfma<0, 64, 128><<<dim3(16, 32), 256, 0, stream>>>(attn_b, Wout_t, b_out, out, nullptr,
                                                          4096, 1024, 1024, 1024);
}

// Round 16
// 180.178 us; speedup vs baseline: 1.0829x; 1.0115x over previous
//
#include <hip/hip_runtime.h>

// ---------------------------------------------------------------------------
// MHSA bf16-MFMA pipeline v22: B=2, S=2048, D=1024, H=16, HD=64
//   p:  fused prep (z=0: W_qkv^T, z=1: W_out^T, z=2: x f32->bf16)
//   k1: qkv GEMM, tile 128x192, BK=64, 40KB LDS (v19/v21-verified)
//   k3: out GEMM -> f32, 128x64, BK=64 (v22: revert v21's BK=128, +2.6us --
//       barrier-drain halving refuted in BOTH k1 (v20, occupancy cliff) and
//       k3 (v21, flat-negative); GEMMs are LDS-read/MFMA throughput bound)
//   k2: flash attention, v16 EXACT (verified 49.2-50.4us across 6 rounds)
// == v19 configuration via the v21 generic template (both HW-verified). ==
// GEMM template generic over BK: CPR=BK/8 chunks/row; store chunk p of row
// r holds logical p^(r&(CPR-1)) via pre-swizzled global src (LDS dst linear
// per m173); read chunk (kk*4+quad)^(l16&(CPR-1)); 2-way alias free (m136).
// Frag layouts (m89/m91): x32: A[m=l16][k=quad*8+j], B[k=quad*8+j][n=l16];
// C: col=l16, row=quad*4+i.
// P redistribution (HW-validated v8/v12/v16): permlane32+16 swap pairs.
// NOTE: v15's v_cvt_pk_bf16_f32 REVERTED permanently (absmax 13.7).
// Session rules learned: GEMM LDS <= 64KB/block (2 blocks/CU); attn v16
// structure is a local optimum (key-split/PV-pipeline/q-split all refuted).
// ws (48 MB): Wout_t 0-2 | qk_bf 2-18 | vT 18-26 | attn_b 26-34 |
//             x_bf 34-42 | Wqkv_t 42-48
// ---------------------------------------------------------------------------

typedef short bf16x8 __attribute__((ext_vector_type(8)));
typedef float f32x4 __attribute__((ext_vector_type(4)));
typedef unsigned uint2v __attribute__((ext_vector_type(2)));

#define MFMA32(a, b, c) __builtin_amdgcn_mfma_f32_16x16x32_bf16(a, b, c, 0, 0, 0)

__device__ __forceinline__ unsigned short f2bf(float f) {   // RNE
  unsigned u = __float_as_uint(f);
  u = (u + 0x7fffu + ((u >> 16) & 1u)) >> 16;
  return (unsigned short)u;
}
__device__ __forceinline__ unsigned pack_bf2(float lo, float hi) {
  unsigned a = __float_as_uint(lo) + 0x8000u;
  unsigned b = __float_as_uint(hi) + 0x8000u;
  return __builtin_amdgcn_perm(b, a, 0x07060302);
}
__device__ __forceinline__ void load_lds16(const unsigned short* g, unsigned short* l) {
  __builtin_amdgcn_global_load_lds(
      (const __attribute__((address_space(1))) void*)g,
      (__attribute__((address_space(3))) void*)l, 16, 0, 0);
}

// Hazard-safe permlane swaps (gfx950), v12/v16-verified on hardware.
#if __has_builtin(__builtin_amdgcn_permlane32_swap)
__device__ __forceinline__ void pl32_swap(unsigned& a, unsigned& b) {
  uint2v r = __builtin_amdgcn_permlane32_swap(a, b, false, false);
  a = r[0]; b = r[1];
}
__device__ __forceinline__ void pl16_swap(unsigned& a, unsigned& b) {
  uint2v r = __builtin_amdgcn_permlane16_swap(a, b, false, false);
  a = r[0]; b = r[1];
}
#else
__device__ __forceinline__ void pl32_swap(unsigned& a, unsigned& b) {
  asm volatile("s_nop 1\n\tv_permlane32_swap_b32 %0, %1\n\ts_nop 1"
               : "+v"(a), "+v"(b));
}
__device__ __forceinline__ void pl16_swap(unsigned& a, unsigned& b) {
  asm volatile("s_nop 1\n\tv_permlane16_swap_b32 %0, %1\n\ts_nop 1"
               : "+v"(a), "+v"(b));
}
#endif

// --- p: fused prep ---------------------------------------------------------
__global__ __launch_bounds__(256) void prep(
    const float* __restrict__ x, unsigned short* __restrict__ x_bf,
    const float* __restrict__ W_qkv, unsigned short* __restrict__ Wqkv_t,
    const float* __restrict__ W_out, unsigned short* __restrict__ Wout_t)
{
  const int tid = threadIdx.x;
  if (blockIdx.z == 2) {
    const int bid = blockIdx.y * 48 + blockIdx.x;          // 0..767
    const int n = 4096 * 1024;
    for (int i = bid * 2048 + tid * 8; i < n; i += 768 * 2048) {
      float4 f0 = *(const float4*)(x + i);
      float4 f1 = *(const float4*)(x + i + 4);
      union { unsigned short u[8]; uint4 v; } pk;
      pk.u[0] = f2bf(f0.x); pk.u[1] = f2bf(f0.y); pk.u[2] = f2bf(f0.z); pk.u[3] = f2bf(f0.w);
      pk.u[4] = f2bf(f1.x); pk.u[5] = f2bf(f1.y); pk.u[6] = f2bf(f1.z); pk.u[7] = f2bf(f1.w);
      *(uint4*)(x_bf + i) = pk.v;
    }
    return;
  }
  const float* in = (blockIdx.z == 0) ? W_qkv : W_out;
  unsigned short* out = (blockIdx.z == 0) ? Wqkv_t : Wout_t;
  const int R = 1024;
  const int C = (blockIdx.z == 0) ? 3072 : 1024;
  const int c0 = blockIdx.x * 64;
  if (c0 >= C) return;
  __shared__ float tile[64][65];
  const int r0 = blockIdx.y * 64;
  {
    const int rr = tid >> 4;
    const int cc = (tid & 15) * 4;
#pragma unroll
    for (int it = 0; it < 4; ++it) {
      float4 f = *(const float4*)&in[(size_t)(r0 + rr + 16 * it) * C + c0 + cc];
      tile[rr + 16 * it][cc + 0] = f.x;
      tile[rr + 16 * it][cc + 1] = f.y;
      tile[rr + 16 * it][cc + 2] = f.z;
      tile[rr + 16 * it][cc + 3] = f.w;
    }
  }
  __syncthreads();
  {
    const int cr = tid >> 2;
    const int rk = (tid & 3) * 16;
    union { unsigned short u[16]; uint4 v[2]; } pk;
#pragma unroll
    for (int j = 0; j < 16; ++j) pk.u[j] = f2bf(tile[rk + j][cr]);
    uint4* dst = (uint4*)&out[(size_t)(c0 + cr) * R + r0 + rk];
    dst[0] = pk.v[0];
    dst[1] = pk.v[1];
  }
}

// --- k1/k3: GEMM C = A[M,K] @ Bt[N,K]^T + bias -----------------------------
// Tile 128 x NB, K-step BK. XOR-swizzled LDS (CPR=BK/8 chunks/row), XCD
// remap. MODE 0: f32 out (ldc = N). MODE 1: bf16: cols<1024 Q (scaled
// log2e/8), 1024..2047 K -> qk_bf; >=2048 V -> vT.
template <int MODE, int NB, int BK>
__global__ __launch_bounds__(256) void gemm_mfma(
    const unsigned short* __restrict__ A,
    const unsigned short* __restrict__ Bt,
    const float* __restrict__ bias,
    void* __restrict__ Cout, unsigned short* __restrict__ vT,
    int M, int N, int K, int ldc)
{
  constexpr int NI = NB / 32;
  constexpr int CPR = BK / 8;              // 16B chunks per row
  constexpr int RPC = 64 / CPR;            // rows staged per load call
  __shared__ unsigned short As[128][BK];
  __shared__ unsigned short Bs[NB][BK];
  const int tid = threadIdx.x;
  const int wave = tid >> 6, lane = tid & 63;
  const int l16 = lane & 15, quad = lane >> 4;

  // XCD-aware bijective block remap (nwg % 8 == 0 for both k1 and k3)
  const int bid = blockIdx.y * gridDim.x + blockIdx.x;
  const int nwg = gridDim.x * gridDim.y;
  const int sbid = (bid & 7) * (nwg >> 3) + (bid >> 3);
  const int bx = sbid % gridDim.x;
  const int by = sbid / gridDim.x;
  const int m0 = by * 128, n0 = bx * NB;

  const int wm = (wave & 1) * 64, wn = (wave >> 1) * (NB / 2);
  // staging: lane -> row lr (0..RPC-1), chunk p (0..CPR-1); stored chunk p
  // of row r holds logical p^(r&(CPR-1)) via pre-swizzled GLOBAL source
  // (LDS dst linear per m173)
  const int lr = lane / CPR;
  const int p  = lane % CPR;
  const int swk = l16 & (CPR - 1);         // read-side swizzle key

  f32x4 acc[4][NI] = {};

  for (int k0 = 0; k0 < K; k0 += BK) {
    __syncthreads();
#pragma unroll
    for (int i = 0; i < 32 / RPC; ++i) {   // A: 32 rows per wave
      const int rbase = wave * 32 + i * RPC;
      const int rl = rbase + lr;
      load_lds16(&A[(size_t)(m0 + rl) * K + k0 + ((p ^ (rl & (CPR - 1))) << 3)],
                 &As[rbase][0]);
    }
#pragma unroll
    for (int i = 0; i < (NB / 4) / RPC; ++i) {  // B: NB/4 rows per wave
      const int rbase = wave * (NB / 4) + i * RPC;
      const int rl = rbase + lr;
      load_lds16(&Bt[(size_t)(n0 + rl) * K + k0 + ((p ^ (rl & (CPR - 1))) << 3)],
                 &Bs[rbase][0]);
    }
    __syncthreads();

#pragma unroll
    for (int kk = 0; kk < BK / 32; ++kk) {
      bf16x8 af[4], bfr[NI];
#pragma unroll
      for (int mi = 0; mi < 4; ++mi)
        af[mi] = *(const bf16x8*)&As[wm + 16 * mi + l16][(((kk << 2) + quad) ^ swk) * 8];
#pragma unroll
      for (int ni = 0; ni < NI; ++ni)
        bfr[ni] = *(const bf16x8*)&Bs[wn + 16 * ni + l16][(((kk << 2) + quad) ^ swk) * 8];
#pragma unroll
      for (int mi = 0; mi < 4; ++mi)
#pragma unroll
        for (int ni = 0; ni < NI; ++ni)
          acc[mi][ni] = __builtin_amdgcn_mfma_f32_16x16x32_bf16(
              af[mi], bfr[ni], acc[mi][ni], 0, 0, 0);
    }
  }

  const float SCQ = 0.18033688f;   // log2(e)/sqrt(64), folded into Q
#pragma unroll
  for (int ni = 0; ni < NI; ++ni) {
    const int colb = n0 + wn + 16 * ni;
    const int col = colb + l16;
    const float bv = bias[col];
    if (MODE == 0) {
#pragma unroll
      for (int mi = 0; mi < 4; ++mi)
#pragma unroll
        for (int i = 0; i < 4; ++i) {
          const int row = m0 + wm + 16 * mi + quad * 4 + i;
          ((float*)Cout)[(size_t)row * ldc + col] = acc[mi][ni][i] + bv;
        }
    } else if (colb < 1024) {          // Q: pre-scale for exp2 softmax
#pragma unroll
      for (int mi = 0; mi < 4; ++mi)
#pragma unroll
        for (int i = 0; i < 4; ++i) {
          const int row = m0 + wm + 16 * mi + quad * 4 + i;
          ((unsigned short*)Cout)[(size_t)row * ldc + col] = f2bf((acc[mi][ni][i] + bv) * SCQ);
        }
    } else if (colb < 2048) {          // K
#pragma unroll
      for (int mi = 0; mi < 4; ++mi)
#pragma unroll
        for (int i = 0; i < 4; ++i) {
          const int row = m0 + wm + 16 * mi + quad * 4 + i;
          ((unsigned short*)Cout)[(size_t)row * ldc + col] = f2bf(acc[mi][ni][i] + bv);
        }
    } else {                           // V -> vT[bh][d][t], packed pairs in t
      const int h = (col - 2048) >> 6, d = col & 63;
#pragma unroll
      for (int mi = 0; mi < 4; ++mi) {
        const int row = m0 + wm + 16 * mi + quad * 4;   // +i, i=0..3
        const int bb = row >> 11, t = row & 2047;
        unsigned short* dst = &vT[((size_t)(bb * 16 + h) * 64 + d) * 2048 + t];
        *(unsigned*)(dst)     = pack_bf2(acc[mi][ni][0] + bv, acc[mi][ni][1] + bv);
        *(unsigned*)(dst + 2) = pack_bf2(acc[mi][ni][2] + bv, acc[mi][ni][3] + bv);
      }
    }
  }
}

// --- k2: flash attention, v16 EXACT (verified 49.2-50.4 us) ----------------
// Block = 4 waves; wave w: q rows [bx*128 + 32w, +32), all 2048 keys.
// K,V tiles (64x64 bf16) double-buffered in LDS; staging goes global->VGPR
// (issued one iter ahead) -> ds_write; per-iter barrier. XOR chunk swizzle
// (chunk c of row r at c ^ (r&7)). S^T = K Q^T (x32); P -> x32 B-frags via
// pack_bf2 + permlane swaps; PV and l via x32 MFMA.
__global__ __launch_bounds__(256, 2) void attn_mfma(
    const unsigned short* __restrict__ qk,    // [4096][2048] (Q|K)
    const unsigned short* __restrict__ vT,    // [32][64][2048]
    unsigned short* __restrict__ attn_out)    // [4096][1024]
{
  __shared__ unsigned short Ks[2][4096];
  __shared__ unsigned short Vs[2][4096];

  const int tid = threadIdx.x;
  const int wave = tid >> 6, lane = tid & 63;
  const int l16 = lane & 15, quad = lane >> 4;
  const int bh = blockIdx.y, b = bh >> 4, h = bh & 15;
  const int s0 = blockIdx.x * 128 + wave * 32;

  const unsigned short* qb = qk + (size_t)(b * 2048) * 2048 + h * 64;
  const unsigned short* kb = qb + 1024;
  const unsigned short* vb = vT + (size_t)bh * 64 * 2048;

  // staging geometry (16B per lane, swizzled chunks)
  const int srow = lane >> 3;                     // 0..7
  const int schunk = ((lane & 7) ^ srow) * 8;     // swizzled 16B chunk
  const int r0a = wave * 16;
  const unsigned short* kg0 = kb + (size_t)(r0a + srow) * 2048 + schunk;
  const unsigned short* kg1 = kg0 + (size_t)8 * 2048;
  const unsigned short* vg0 = vb + (size_t)(r0a + srow) * 2048 + schunk;
  const unsigned short* vg1 = vg0 + (size_t)8 * 2048;
  const int wd0 = r0a * 64 + lane * 8;            // LDS dst (shorts)
  const int wd1 = (r0a + 8) * 64 + lane * 8;

  // tile 0 -> buf 0; tile 1 into regs (in flight across first compute)
  uint4 kr0 = *(const uint4*)(kg0);
  uint4 kr1 = *(const uint4*)(kg1);
  uint4 vr0 = *(const uint4*)(vg0);
  uint4 vr1 = *(const uint4*)(vg1);
  *(uint4*)&Ks[0][wd0] = kr0;  *(uint4*)&Ks[0][wd1] = kr1;
  *(uint4*)&Vs[0][wd0] = vr0;  *(uint4*)&Vs[0][wd1] = vr1;
  kr0 = *(const uint4*)(kg0 + (size_t)64 * 2048);
  kr1 = *(const uint4*)(kg1 + (size_t)64 * 2048);
  vr0 = *(const uint4*)(vg0 + 64);
  vr1 = *(const uint4*)(vg1 + 64);

  // Q frags (x32 B-layout: k=d, n=q); Q pre-scaled by log2e/8
  bf16x8 qf[2][2];
#pragma unroll
  for (int mt = 0; mt < 2; ++mt)
#pragma unroll
    for (int ks = 0; ks < 2; ++ks)
      qf[mt][ks] = *(const bf16x8*)&qb[(size_t)(s0 + 16 * mt + l16) * 2048 + 32 * ks + quad * 8];

  f32x4 O[2][4] = {};      // O^T accum: [mt][nd], C col=q=l16, row=d local
  f32x4 lacc[2] = {};      // l via ones-MFMA (rows replicated)
  const bf16x8 ones8 = {(short)0x3F80, (short)0x3F80, (short)0x3F80, (short)0x3F80,
                        (short)0x3F80, (short)0x3F80, (short)0x3F80, (short)0x3F80};
  const int sw = l16 & 7;

  __syncthreads();

  for (int it = 0; it < 32; ++it) {
    const int cur = it & 1;

    // ---- K frags (x32 A-layout: m=t, k=d) from swizzled LDS ----
    bf16x8 kf[4][2];
#pragma unroll
    for (int nt = 0; nt < 4; ++nt) {
      const int rb = (16 * nt + l16) * 64;
      kf[nt][0] = *(const bf16x8*)&Ks[cur][rb + ((quad ^ sw) * 8)];
      kf[nt][1] = *(const bf16x8*)&Ks[cur][rb + (((4 + quad) ^ sw) * 8)];
    }

    // ---- S^T = K Q^T (x32): C row=t=quad*4+i, col=q=l16 ----
    f32x4 sf[4][2];
#pragma unroll
    for (int nt = 0; nt < 4; ++nt)
#pragma unroll
      for (int mt = 0; mt < 2; ++mt) {
        f32x4 c = {0.0f, 0.0f, 0.0f, 0.0f};
        c = __builtin_amdgcn_mfma_f32_16x16x32_bf16(kf[nt][0], qf[mt][0], c, 0, 0, 0);
        c = __builtin_amdgcn_mfma_f32_16x16x32_bf16(kf[nt][1], qf[mt][1], c, 0, 0, 0);
        sf[nt][mt] = c;
      }

    // ---- stage tile it+1 (regs -> other buffer); prefetch tile it+2 ----
    if (it < 31) {
      *(uint4*)&Ks[cur ^ 1][wd0] = kr0;
      *(uint4*)&Ks[cur ^ 1][wd1] = kr1;
      *(uint4*)&Vs[cur ^ 1][wd0] = vr0;
      *(uint4*)&Vs[cur ^ 1][wd1] = vr1;
      if (it < 30) {
        const size_t ko = (size_t)(it + 2) * 64 * 2048;
        kr0 = *(const uint4*)(kg0 + ko);
        kr1 = *(const uint4*)(kg1 + ko);
        vr0 = *(const uint4*)(vg0 + (it + 2) * 64);
        vr1 = *(const uint4*)(vg1 + (it + 2) * 64);
      }
    }

    // ---- V frags (x32 A-layout: m=d, k=t): same swizzle as K ----
    bf16x8 vf[4][2];
#pragma unroll
    for (int nd = 0; nd < 4; ++nd) {
      const int rb = (16 * nd + l16) * 64;
      vf[nd][0] = *(const bf16x8*)&Vs[cur][rb + ((quad ^ sw) * 8)];
      vf[nd][1] = *(const bf16x8*)&Vs[cur][rb + (((4 + quad) ^ sw) * 8)];
    }

    // ---- p = exp2(s); pack_bf2; permlane-redistribute to x32 B-frags ----
    bf16x8 pB[2][2];   // [mt][c]
#pragma unroll
    for (int mt = 0; mt < 2; ++mt)
#pragma unroll
      for (int c = 0; c < 2; ++c) {
        const f32x4 sa = sf[2 * c][mt];
        const f32x4 sb = sf[2 * c + 1][mt];
        unsigned X = pack_bf2(__builtin_amdgcn_exp2f(sa[0]), __builtin_amdgcn_exp2f(sa[1]));
        unsigned Y = pack_bf2(__builtin_amdgcn_exp2f(sa[2]), __builtin_amdgcn_exp2f(sa[3]));
        unsigned Z = pack_bf2(__builtin_amdgcn_exp2f(sb[0]), __builtin_amdgcn_exp2f(sb[1]));
        unsigned W = pack_bf2(__builtin_amdgcn_exp2f(sb[2]), __builtin_amdgcn_exp2f(sb[3]));
        pl32_swap(X, Z);
        pl16_swap(X, Z);
        pl32_swap(Y, W);
        pl16_swap(Y, W);
        union { unsigned u[4]; bf16x8 v; } pk;
        pk.u[0] = X; pk.u[1] = Y; pk.u[2] = Z; pk.u[3] = W;
        pB[mt][c] = pk.v;
      }

    // ---- O^T += V^T P^T (x32); l += ones P^T (x32) ----
#pragma unroll
    for (int c = 0; c < 2; ++c)
#pragma unroll
      for (int mt = 0; mt < 2; ++mt) {
        lacc[mt] = MFMA32(ones8, pB[mt][c], lacc[mt]);
#pragma unroll
        for (int nd = 0; nd < 4; ++nd)
          O[mt][nd] = MFMA32(vf[nd][c], pB[mt][c], O[mt][nd]);
      }

    __syncthreads();
  }

  // ---- epilogue: lane holds q=s0+16mt+l16, d=16nd+quad*4+{0..3} ----
#pragma unroll
  for (int mt = 0; mt < 2; ++mt) {
    const float inv = 1.0f / lacc[mt][0];
    const size_t row = (size_t)(b * 2048 + s0 + 16 * mt + l16);
#pragma unroll
    for (int nd = 0; nd < 4; ++nd) {
      uint2 w;
      w.x = pack_bf2(O[mt][nd][0] * inv, O[mt][nd][1] * inv);
      w.y = pack_bf2(O[mt][nd][2] * inv, O[mt][nd][3] * inv);
      *(uint2*)&attn_out[row * 1024 + h * 64 + 16 * nd + quad * 4] = w;
    }
  }
}

extern "C" void kernel_launch(void* const* d_in, const int* in_sizes, int n_in,
                              void* d_out, int out_size, void* d_ws, size_t ws_size,
                              hipStream_t stream) {
  const float* x     = (const float*)d_in[0];
  const float* W_qkv = (const float*)d_in[1];
  const float* b_qkv = (const float*)d_in[2];
  const float* W_out = (const float*)d_in[3];
  const float* b_out = (const float*)d_in[4];
  float* out = (float*)d_out;

  char* ws = (char*)d_ws;
  const size_t MB = 1048576;
  unsigned short* Wout_t = (unsigned short*)(ws);             //  0-2 MB
  unsigned short* qk_bf  = (unsigned short*)(ws + 2 * MB);    //  2-18 MB
  unsigned short* vT     = (unsigned short*)(ws + 18 * MB);   // 18-26 MB
  unsigned short* attn_b = (unsigned short*)(ws + 26 * MB);   // 26-34 MB
  unsigned short* x_bf   = (unsigned short*)(ws + 34 * MB);   // 34-42 MB
  unsigned short* Wqkv_t = (unsigned short*)(ws + 42 * MB);   // 42-48 MB

  prep<<<dim3(48, 16, 3), 256, 0, stream>>>(x, x_bf, W_qkv, Wqkv_t, W_out, Wout_t);

  gemm_mfma<1, 192, 64><<<dim3(16, 32), 256, 0, stream>>>(x_bf, Wqkv_t, b_qkv, qk_bf, vT,
                                                          4096, 3072, 1024, 2048);
  attn_mfma<<<dim3(16, 32), 256, 0, stream>>>(qk_bf, vT, attn_b);
  gemm_mfma<0, 64, 64><<<dim3(16, 32), 256, 0, stream>>>(attn_b, Wout_t, b_out, out, nullptr,
                                                         4096, 1024, 1024, 1024);
}

// Round 17
// 178.642 us; speedup vs baseline: 1.0922x; 1.0086x over previous
//
#include <hip/hip_runtime.h>

// ---------------------------------------------------------------------------
// MHSA bf16-MFMA pipeline v23: B=2, S=2048, D=1024, H=16, HD=64
//   p:  fused prep (z=0: W_qkv^T, z=1: W_out^T, z=2: x f32->bf16)
//   k1: qkv GEMM, tile 128x192, BK=64, 40KB LDS (v19/v22-verified)
//   k3: out GEMM -> f32, 128x64, BK=64 (v22-verified)
//   k2: flash attention, v23 change: KVBLK=128 via TWO 64-key sub-tiles per
//       double buffer (Ks/Vs[2][2][4096], 64KB LDS, still 2 blocks/CU per
//       v12 evidence). The verified v16 64-key body runs twice per barrier:
//       barriers 32 -> 16, each drain amortized over 2x independent work.
//       Per-key work:staging ratio unchanged (v17 failure mode absent); no
//       cross-barrier P state (v14 failure mode absent); all per-sub-tile
//       addressing byte-identical to v16.
// GEMM template generic over BK: CPR=BK/8 chunks/row; store chunk p of row
// r holds logical p^(r&(CPR-1)) via pre-swizzled global src (LDS dst linear
// per m173); read chunk (kk*4+quad)^(l16&(CPR-1)); 2-way alias free (m136).
// Frag layouts (m89/m91): x32: A[m=l16][k=quad*8+j], B[k=quad*8+j][n=l16];
// C: col=l16, row=quad*4+i.
// P redistribution (HW-validated v8/v12/v16): permlane32+16 swap pairs.
// NOTE: v15's v_cvt_pk_bf16_f32 REVERTED permanently (absmax 13.7).
// Session rules: GEMM LDS <= 64KB/block (2 blocks/CU); GEMM barrier-halving
// refuted (v20 occupancy cliff, v21 flat); attn key-split/PV-pipe/q-split
// refuted (v12/v14/v17).
// ws (48 MB): Wout_t 0-2 | qk_bf 2-18 | vT 18-26 | attn_b 26-34 |
//             x_bf 34-42 | Wqkv_t 42-48
// ---------------------------------------------------------------------------

typedef short bf16x8 __attribute__((ext_vector_type(8)));
typedef float f32x4 __attribute__((ext_vector_type(4)));
typedef unsigned uint2v __attribute__((ext_vector_type(2)));

#define MFMA32(a, b, c) __builtin_amdgcn_mfma_f32_16x16x32_bf16(a, b, c, 0, 0, 0)

__device__ __forceinline__ unsigned short f2bf(float f) {   // RNE
  unsigned u = __float_as_uint(f);
  u = (u + 0x7fffu + ((u >> 16) & 1u)) >> 16;
  return (unsigned short)u;
}
__device__ __forceinline__ unsigned pack_bf2(float lo, float hi) {
  unsigned a = __float_as_uint(lo) + 0x8000u;
  unsigned b = __float_as_uint(hi) + 0x8000u;
  return __builtin_amdgcn_perm(b, a, 0x07060302);
}
__device__ __forceinline__ void load_lds16(const unsigned short* g, unsigned short* l) {
  __builtin_amdgcn_global_load_lds(
      (const __attribute__((address_space(1))) void*)g,
      (__attribute__((address_space(3))) void*)l, 16, 0, 0);
}

// Hazard-safe permlane swaps (gfx950), v12/v16-verified on hardware.
#if __has_builtin(__builtin_amdgcn_permlane32_swap)
__device__ __forceinline__ void pl32_swap(unsigned& a, unsigned& b) {
  uint2v r = __builtin_amdgcn_permlane32_swap(a, b, false, false);
  a = r[0]; b = r[1];
}
__device__ __forceinline__ void pl16_swap(unsigned& a, unsigned& b) {
  uint2v r = __builtin_amdgcn_permlane16_swap(a, b, false, false);
  a = r[0]; b = r[1];
}
#else
__device__ __forceinline__ void pl32_swap(unsigned& a, unsigned& b) {
  asm volatile("s_nop 1\n\tv_permlane32_swap_b32 %0, %1\n\ts_nop 1"
               : "+v"(a), "+v"(b));
}
__device__ __forceinline__ void pl16_swap(unsigned& a, unsigned& b) {
  asm volatile("s_nop 1\n\tv_permlane16_swap_b32 %0, %1\n\ts_nop 1"
               : "+v"(a), "+v"(b));
}
#endif

// --- p: fused prep ---------------------------------------------------------
__global__ __launch_bounds__(256) void prep(
    const float* __restrict__ x, unsigned short* __restrict__ x_bf,
    const float* __restrict__ W_qkv, unsigned short* __restrict__ Wqkv_t,
    const float* __restrict__ W_out, unsigned short* __restrict__ Wout_t)
{
  const int tid = threadIdx.x;
  if (blockIdx.z == 2) {
    const int bid = blockIdx.y * 48 + blockIdx.x;          // 0..767
    const int n = 4096 * 1024;
    for (int i = bid * 2048 + tid * 8; i < n; i += 768 * 2048) {
      float4 f0 = *(const float4*)(x + i);
      float4 f1 = *(const float4*)(x + i + 4);
      union { unsigned short u[8]; uint4 v; } pk;
      pk.u[0] = f2bf(f0.x); pk.u[1] = f2bf(f0.y); pk.u[2] = f2bf(f0.z); pk.u[3] = f2bf(f0.w);
      pk.u[4] = f2bf(f1.x); pk.u[5] = f2bf(f1.y); pk.u[6] = f2bf(f1.z); pk.u[7] = f2bf(f1.w);
      *(uint4*)(x_bf + i) = pk.v;
    }
    return;
  }
  const float* in = (blockIdx.z == 0) ? W_qkv : W_out;
  unsigned short* out = (blockIdx.z == 0) ? Wqkv_t : Wout_t;
  const int R = 1024;
  const int C = (blockIdx.z == 0) ? 3072 : 1024;
  const int c0 = blockIdx.x * 64;
  if (c0 >= C) return;
  __shared__ float tile[64][65];
  const int r0 = blockIdx.y * 64;
  {
    const int rr = tid >> 4;
    const int cc = (tid & 15) * 4;
#pragma unroll
    for (int it = 0; it < 4; ++it) {
      float4 f = *(const float4*)&in[(size_t)(r0 + rr + 16 * it) * C + c0 + cc];
      tile[rr + 16 * it][cc + 0] = f.x;
      tile[rr + 16 * it][cc + 1] = f.y;
      tile[rr + 16 * it][cc + 2] = f.z;
      tile[rr + 16 * it][cc + 3] = f.w;
    }
  }
  __syncthreads();
  {
    const int cr = tid >> 2;
    const int rk = (tid & 3) * 16;
    union { unsigned short u[16]; uint4 v[2]; } pk;
#pragma unroll
    for (int j = 0; j < 16; ++j) pk.u[j] = f2bf(tile[rk + j][cr]);
    uint4* dst = (uint4*)&out[(size_t)(c0 + cr) * R + r0 + rk];
    dst[0] = pk.v[0];
    dst[1] = pk.v[1];
  }
}

// --- k1/k3: GEMM C = A[M,K] @ Bt[N,K]^T + bias -----------------------------
// Tile 128 x NB, K-step BK. XOR-swizzled LDS (CPR=BK/8 chunks/row), XCD
// remap. MODE 0: f32 out (ldc = N). MODE 1: bf16: cols<1024 Q (scaled
// log2e/8), 1024..2047 K -> qk_bf; >=2048 V -> vT.
template <int MODE, int NB, int BK>
__global__ __launch_bounds__(256) void gemm_mfma(
    const unsigned short* __restrict__ A,
    const unsigned short* __restrict__ Bt,
    const float* __restrict__ bias,
    void* __restrict__ Cout, unsigned short* __restrict__ vT,
    int M, int N, int K, int ldc)
{
  constexpr int NI = NB / 32;
  constexpr int CPR = BK / 8;              // 16B chunks per row
  constexpr int RPC = 64 / CPR;            // rows staged per load call
  __shared__ unsigned short As[128][BK];
  __shared__ unsigned short Bs[NB][BK];
  const int tid = threadIdx.x;
  const int wave = tid >> 6, lane = tid & 63;
  const int l16 = lane & 15, quad = lane >> 4;

  // XCD-aware bijective block remap (nwg % 8 == 0 for both k1 and k3)
  const int bid = blockIdx.y * gridDim.x + blockIdx.x;
  const int nwg = gridDim.x * gridDim.y;
  const int sbid = (bid & 7) * (nwg >> 3) + (bid >> 3);
  const int bx = sbid % gridDim.x;
  const int by = sbid / gridDim.x;
  const int m0 = by * 128, n0 = bx * NB;

  const int wm = (wave & 1) * 64, wn = (wave >> 1) * (NB / 2);
  const int lr = lane / CPR;
  const int p  = lane % CPR;
  const int swk = l16 & (CPR - 1);         // read-side swizzle key

  f32x4 acc[4][NI] = {};

  for (int k0 = 0; k0 < K; k0 += BK) {
    __syncthreads();
#pragma unroll
    for (int i = 0; i < 32 / RPC; ++i) {   // A: 32 rows per wave
      const int rbase = wave * 32 + i * RPC;
      const int rl = rbase + lr;
      load_lds16(&A[(size_t)(m0 + rl) * K + k0 + ((p ^ (rl & (CPR - 1))) << 3)],
                 &As[rbase][0]);
    }
#pragma unroll
    for (int i = 0; i < (NB / 4) / RPC; ++i) {  // B: NB/4 rows per wave
      const int rbase = wave * (NB / 4) + i * RPC;
      const int rl = rbase + lr;
      load_lds16(&Bt[(size_t)(n0 + rl) * K + k0 + ((p ^ (rl & (CPR - 1))) << 3)],
                 &Bs[rbase][0]);
    }
    __syncthreads();

#pragma unroll
    for (int kk = 0; kk < BK / 32; ++kk) {
      bf16x8 af[4], bfr[NI];
#pragma unroll
      for (int mi = 0; mi < 4; ++mi)
        af[mi] = *(const bf16x8*)&As[wm + 16 * mi + l16][(((kk << 2) + quad) ^ swk) * 8];
#pragma unroll
      for (int ni = 0; ni < NI; ++ni)
        bfr[ni] = *(const bf16x8*)&Bs[wn + 16 * ni + l16][(((kk << 2) + quad) ^ swk) * 8];
#pragma unroll
      for (int mi = 0; mi < 4; ++mi)
#pragma unroll
        for (int ni = 0; ni < NI; ++ni)
          acc[mi][ni] = __builtin_amdgcn_mfma_f32_16x16x32_bf16(
              af[mi], bfr[ni], acc[mi][ni], 0, 0, 0);
    }
  }

  const float SCQ = 0.18033688f;   // log2(e)/sqrt(64), folded into Q
#pragma unroll
  for (int ni = 0; ni < NI; ++ni) {
    const int colb = n0 + wn + 16 * ni;
    const int col = colb + l16;
    const float bv = bias[col];
    if (MODE == 0) {
#pragma unroll
      for (int mi = 0; mi < 4; ++mi)
#pragma unroll
        for (int i = 0; i < 4; ++i) {
          const int row = m0 + wm + 16 * mi + quad * 4 + i;
          ((float*)Cout)[(size_t)row * ldc + col] = acc[mi][ni][i] + bv;
        }
    } else if (colb < 1024) {          // Q: pre-scale for exp2 softmax
#pragma unroll
      for (int mi = 0; mi < 4; ++mi)
#pragma unroll
        for (int i = 0; i < 4; ++i) {
          const int row = m0 + wm + 16 * mi + quad * 4 + i;
          ((unsigned short*)Cout)[(size_t)row * ldc + col] = f2bf((acc[mi][ni][i] + bv) * SCQ);
        }
    } else if (colb < 2048) {          // K
#pragma unroll
      for (int mi = 0; mi < 4; ++mi)
#pragma unroll
        for (int i = 0; i < 4; ++i) {
          const int row = m0 + wm + 16 * mi + quad * 4 + i;
          ((unsigned short*)Cout)[(size_t)row * ldc + col] = f2bf(acc[mi][ni][i] + bv);
        }
    } else {                           // V -> vT[bh][d][t], packed pairs in t
      const int h = (col - 2048) >> 6, d = col & 63;
#pragma unroll
      for (int mi = 0; mi < 4; ++mi) {
        const int row = m0 + wm + 16 * mi + quad * 4;   // +i, i=0..3
        const int bb = row >> 11, t = row & 2047;
        unsigned short* dst = &vT[((size_t)(bb * 16 + h) * 64 + d) * 2048 + t];
        *(unsigned*)(dst)     = pack_bf2(acc[mi][ni][0] + bv, acc[mi][ni][1] + bv);
        *(unsigned*)(dst + 2) = pack_bf2(acc[mi][ni][2] + bv, acc[mi][ni][3] + bv);
      }
    }
  }
}

// --- k2: flash attention, KVBLK=128 (2 sub-tiles per barrier) --------------
// Block = 4 waves; wave w: q rows [bx*128 + 32w, +32), all 2048 keys.
// Ks/Vs[buf][sub][4096]: 64KB. Iteration it processes sub-tiles 2it, 2it+1
// from buf[it&1] (each the verified v16 64-key body), stages tiles
// 2it+2/2it+3 into buf[it&1^1], prefetches 2it+4/2it+5 into regs. ONE
// barrier per 128 keys (16 total, was 32). XOR chunk swizzle per sub-tile.
__global__ __launch_bounds__(256, 2) void attn_mfma(
    const unsigned short* __restrict__ qk,    // [4096][2048] (Q|K)
    const unsigned short* __restrict__ vT,    // [32][64][2048]
    unsigned short* __restrict__ attn_out)    // [4096][1024]
{
  __shared__ unsigned short Ks[2][2][4096];
  __shared__ unsigned short Vs[2][2][4096];

  const int tid = threadIdx.x;
  const int wave = tid >> 6, lane = tid & 63;
  const int l16 = lane & 15, quad = lane >> 4;
  const int bh = blockIdx.y, b = bh >> 4, h = bh & 15;
  const int s0 = blockIdx.x * 128 + wave * 32;

  const unsigned short* qb = qk + (size_t)(b * 2048) * 2048 + h * 64;
  const unsigned short* kb = qb + 1024;
  const unsigned short* vb = vT + (size_t)bh * 64 * 2048;

  // staging geometry (16B per lane, swizzled chunks) -- per 64-key sub-tile
  const int srow = lane >> 3;                     // 0..7
  const int schunk = ((lane & 7) ^ srow) * 8;     // swizzled 16B chunk
  const int r0a = wave * 16;
  const unsigned short* kg0 = kb + (size_t)(r0a + srow) * 2048 + schunk;
  const unsigned short* kg1 = kg0 + (size_t)8 * 2048;
  const unsigned short* vg0 = vb + (size_t)(r0a + srow) * 2048 + schunk;
  const unsigned short* vg1 = vg0 + (size_t)8 * 2048;
  const int wd0 = r0a * 64 + lane * 8;            // LDS dst (shorts)
  const int wd1 = (r0a + 8) * 64 + lane * 8;

  // prologue: tiles 0,1 -> buf0 sub0/1; tiles 2,3 -> regs (in flight)
  uint4 kr0 = *(const uint4*)(kg0);
  uint4 kr1 = *(const uint4*)(kg1);
  uint4 vr0 = *(const uint4*)(vg0);
  uint4 vr1 = *(const uint4*)(vg1);
  *(uint4*)&Ks[0][0][wd0] = kr0;  *(uint4*)&Ks[0][0][wd1] = kr1;
  *(uint4*)&Vs[0][0][wd0] = vr0;  *(uint4*)&Vs[0][0][wd1] = vr1;
  kr0 = *(const uint4*)(kg0 + (size_t)64 * 2048);
  kr1 = *(const uint4*)(kg1 + (size_t)64 * 2048);
  vr0 = *(const uint4*)(vg0 + 64);
  vr1 = *(const uint4*)(vg1 + 64);
  *(uint4*)&Ks[0][1][wd0] = kr0;  *(uint4*)&Ks[0][1][wd1] = kr1;
  *(uint4*)&Vs[0][1][wd0] = vr0;  *(uint4*)&Vs[0][1][wd1] = vr1;
  kr0 = *(const uint4*)(kg0 + (size_t)2 * 64 * 2048);
  kr1 = *(const uint4*)(kg1 + (size_t)2 * 64 * 2048);
  vr0 = *(const uint4*)(vg0 + 128);
  vr1 = *(const uint4*)(vg1 + 128);
  uint4 kr2 = *(const uint4*)(kg0 + (size_t)3 * 64 * 2048);
  uint4 kr3 = *(const uint4*)(kg1 + (size_t)3 * 64 * 2048);
  uint4 vr2 = *(const uint4*)(vg0 + 192);
  uint4 vr3 = *(const uint4*)(vg1 + 192);

  // Q frags (x32 B-layout: k=d, n=q); Q pre-scaled by log2e/8
  bf16x8 qf[2][2];
#pragma unroll
  for (int mt = 0; mt < 2; ++mt)
#pragma unroll
    for (int ks = 0; ks < 2; ++ks)
      qf[mt][ks] = *(const bf16x8*)&qb[(size_t)(s0 + 16 * mt + l16) * 2048 + 32 * ks + quad * 8];

  f32x4 O[2][4] = {};      // O^T accum: [mt][nd], C col=q=l16, row=d local
  f32x4 lacc[2] = {};      // l via ones-MFMA (rows replicated)
  const bf16x8 ones8 = {(short)0x3F80, (short)0x3F80, (short)0x3F80, (short)0x3F80,
                        (short)0x3F80, (short)0x3F80, (short)0x3F80, (short)0x3F80};
  const int sw = l16 & 7;

  __syncthreads();

  for (int it = 0; it < 16; ++it) {
    const int cur = it & 1;

#pragma unroll
    for (int s = 0; s < 2; ++s) {
      // ---- K frags (x32 A-layout: m=t, k=d) from swizzled LDS ----
      bf16x8 kf[4][2];
#pragma unroll
      for (int nt = 0; nt < 4; ++nt) {
        const int rb = (16 * nt + l16) * 64;
        kf[nt][0] = *(const bf16x8*)&Ks[cur][s][rb + ((quad ^ sw) * 8)];
        kf[nt][1] = *(const bf16x8*)&Ks[cur][s][rb + (((4 + quad) ^ sw) * 8)];
      }

      // ---- S^T = K Q^T (x32): C row=t=quad*4+i, col=q=l16 ----
      f32x4 sf[4][2];
#pragma unroll
      for (int nt = 0; nt < 4; ++nt)
#pragma unroll
        for (int mt = 0; mt < 2; ++mt) {
          f32x4 c = {0.0f, 0.0f, 0.0f, 0.0f};
          c = __builtin_amdgcn_mfma_f32_16x16x32_bf16(kf[nt][0], qf[mt][0], c, 0, 0, 0);
          c = __builtin_amdgcn_mfma_f32_16x16x32_bf16(kf[nt][1], qf[mt][1], c, 0, 0, 0);
          sf[nt][mt] = c;
        }

      // ---- stage tile 2it+2+s (regs -> buf[cur^1][s]); prefetch 2it+4+s --
      if (it < 15) {
        if (s == 0) {
          *(uint4*)&Ks[cur ^ 1][0][wd0] = kr0;
          *(uint4*)&Ks[cur ^ 1][0][wd1] = kr1;
          *(uint4*)&Vs[cur ^ 1][0][wd0] = vr0;
          *(uint4*)&Vs[cur ^ 1][0][wd1] = vr1;
          if (it < 14) {
            const size_t ko = (size_t)(2 * it + 4) * 64 * 2048;
            kr0 = *(const uint4*)(kg0 + ko);
            kr1 = *(const uint4*)(kg1 + ko);
            vr0 = *(const uint4*)(vg0 + (2 * it + 4) * 64);
            vr1 = *(const uint4*)(vg1 + (2 * it + 4) * 64);
          }
        } else {
          *(uint4*)&Ks[cur ^ 1][1][wd0] = kr2;
          *(uint4*)&Ks[cur ^ 1][1][wd1] = kr3;
          *(uint4*)&Vs[cur ^ 1][1][wd0] = vr2;
          *(uint4*)&Vs[cur ^ 1][1][wd1] = vr3;
          if (it < 14) {
            const size_t ko = (size_t)(2 * it + 5) * 64 * 2048;
            kr2 = *(const uint4*)(kg0 + ko);
            kr3 = *(const uint4*)(kg1 + ko);
            vr2 = *(const uint4*)(vg0 + (2 * it + 5) * 64);
            vr3 = *(const uint4*)(vg1 + (2 * it + 5) * 64);
          }
        }
      }

      // ---- V frags (x32 A-layout: m=d, k=t): same swizzle as K ----
      bf16x8 vf[4][2];
#pragma unroll
      for (int nd = 0; nd < 4; ++nd) {
        const int rb = (16 * nd + l16) * 64;
        vf[nd][0] = *(const bf16x8*)&Vs[cur][s][rb + ((quad ^ sw) * 8)];
        vf[nd][1] = *(const bf16x8*)&Vs[cur][s][rb + (((4 + quad) ^ sw) * 8)];
      }

      // ---- p = exp2(s); pack_bf2; permlane-redistribute to x32 B-frags --
      bf16x8 pB[2][2];   // [mt][c]
#pragma unroll
      for (int mt = 0; mt < 2; ++mt)
#pragma unroll
        for (int c = 0; c < 2; ++c) {
          const f32x4 sa = sf[2 * c][mt];
          const f32x4 sb = sf[2 * c + 1][mt];
          unsigned X = pack_bf2(__builtin_amdgcn_exp2f(sa[0]), __builtin_amdgcn_exp2f(sa[1]));
          unsigned Y = pack_bf2(__builtin_amdgcn_exp2f(sa[2]), __builtin_amdgcn_exp2f(sa[3]));
          unsigned Z = pack_bf2(__builtin_amdgcn_exp2f(sb[0]), __builtin_amdgcn_exp2f(sb[1]));
          unsigned W = pack_bf2(__builtin_amdgcn_exp2f(sb[2]), __builtin_amdgcn_exp2f(sb[3]));
          pl32_swap(X, Z);
          pl16_swap(X, Z);
          pl32_swap(Y, W);
          pl16_swap(Y, W);
          union { unsigned u[4]; bf16x8 v; } pk;
          pk.u[0] = X; pk.u[1] = Y; pk.u[2] = Z; pk.u[3] = W;
          pB[mt][c] = pk.v;
        }

      // ---- O^T += V^T P^T (x32); l += ones P^T (x32) ----
#pragma unroll
      for (int c = 0; c < 2; ++c)
#pragma unroll
        for (int mt = 0; mt < 2; ++mt) {
          lacc[mt] = MFMA32(ones8, pB[mt][c], lacc[mt]);
#pragma unroll
          for (int nd = 0; nd < 4; ++nd)
            O[mt][nd] = MFMA32(vf[nd][c], pB[mt][c], O[mt][nd]);
        }
    }

    __syncthreads();
  }

  // ---- epilogue: lane holds q=s0+16mt+l16, d=16nd+quad*4+{0..3} ----
#pragma unroll
  for (int mt = 0; mt < 2; ++mt) {
    const float inv = 1.0f / lacc[mt][0];
    const size_t row = (size_t)(b * 2048 + s0 + 16 * mt + l16);
#pragma unroll
    for (int nd = 0; nd < 4; ++nd) {
      uint2 w;
      w.x = pack_bf2(O[mt][nd][0] * inv, O[mt][nd][1] * inv);
      w.y = pack_bf2(O[mt][nd][2] * inv, O[mt][nd][3] * inv);
      *(uint2*)&attn_out[row * 1024 + h * 64 + 16 * nd + quad * 4] = w;
    }
  }
}

extern "C" void kernel_launch(void* const* d_in, const int* in_sizes, int n_in,
                              void* d_out, int out_size, void* d_ws, size_t ws_size,
                              hipStream_t stream) {
  const float* x     = (const float*)d_in[0];
  const float* W_qkv = (const float*)d_in[1];
  const float* b_qkv = (const float*)d_in[2];
  const float* W_out = (const float*)d_in[3];
  const float* b_out = (const float*)d_in[4];
  float* out = (float*)d_out;

  char* ws = (char*)d_ws;
  const size_t MB = 1048576;
  unsigned short* Wout_t = (unsigned short*)(ws);             //  0-2 MB
  unsigned short* qk_bf  = (unsigned short*)(ws + 2 * MB);    //  2-18 MB
  unsigned short* vT     = (unsigned short*)(ws + 18 * MB);   // 18-26 MB
  unsigned short* attn_b = (unsigned short*)(ws + 26 * MB);   // 26-34 MB
  unsigned short* x_bf   = (unsigned short*)(ws + 34 * MB);   // 34-42 MB
  unsigned short* Wqkv_t = (unsigned short*)(ws + 42 * MB);   // 42-48 MB

  prep<<<dim3(48, 16, 3), 256, 0, stream>>>(x, x_bf, W_qkv, Wqkv_t, W_out, Wout_t);

  gemm_mfma<1, 192, 64><<<dim3(16, 32), 256, 0, stream>>>(x_bf, Wqkv_t, b_qkv, qk_bf, vT,
                                                          4096, 3072, 1024, 2048);
  attn_mfma<<<dim3(16, 32), 256, 0, stream>>>(qk_bf, vT, attn_b);
  gemm_mfma<0, 64, 64><<<dim3(16, 32), 256, 0, stream>>>(attn_b, Wout_t, b_out, out, nullptr,
                                                         4096, 1024, 1024, 1024);
}

// Round 18
// 175.738 us; speedup vs baseline: 1.1103x; 1.0165x over previous
//
#include <hip/hip_runtime.h>

// ---------------------------------------------------------------------------
// MHSA bf16-MFMA pipeline v24: B=2, S=2048, D=1024, H=16, HD=64
//   p:  fused prep (z=0: W_qkv^T, z=1: W_out^T, z=2: x f32->bf16)
//   k1: qkv GEMM, tile 128x192, BK=64, 40KB LDS (v19/v22-verified)
//   k3: out GEMM -> f32, 128x64, BK=64 (v22-verified)
//   k2: flash attention, KVBLK=128 (v23-verified, 48.3us) + v24 change:
//       XCD-aware block remap (same bijective formula as the GEMMs; 512%8==0).
//       FETCH_SIZE showed 69.7MB vs ~24MB unique working set: the 16 blocks
//       sharing one bh re-fetch the same 512KB K/V panel through different
//       XCD L2s. Chunked remap puts each bh-group on one XCD -> panel
//       fetched once (T1 mechanism).
// GEMM template generic over BK: CPR=BK/8 chunks/row; store chunk p of row
// r holds logical p^(r&(CPR-1)) via pre-swizzled global src (LDS dst linear
// per m173); read chunk (kk*4+quad)^(l16&(CPR-1)); 2-way alias free (m136).
// Frag layouts (m89/m91): x32: A[m=l16][k=quad*8+j], B[k=quad*8+j][n=l16];
// C: col=l16, row=quad*4+i.
// P redistribution (HW-validated v8/v12/v16): permlane32+16 swap pairs.
// NOTE: v15's v_cvt_pk_bf16_f32 REVERTED permanently (absmax 13.7).
// Session rules: GEMM LDS <= 64KB/block (2 blocks/CU); GEMM barrier-halving
// refuted (v20 cliff, v21 flat); attn key-split/PV-pipe/q-split refuted
// (v12/v14/v17); attn KVBLK=256 would need 128KB/block -> refuted territory.
// ws (48 MB): Wout_t 0-2 | qk_bf 2-18 | vT 18-26 | attn_b 26-34 |
//             x_bf 34-42 | Wqkv_t 42-48
// ---------------------------------------------------------------------------

typedef short bf16x8 __attribute__((ext_vector_type(8)));
typedef float f32x4 __attribute__((ext_vector_type(4)));
typedef unsigned uint2v __attribute__((ext_vector_type(2)));

#define MFMA32(a, b, c) __builtin_amdgcn_mfma_f32_16x16x32_bf16(a, b, c, 0, 0, 0)

__device__ __forceinline__ unsigned short f2bf(float f) {   // RNE
  unsigned u = __float_as_uint(f);
  u = (u + 0x7fffu + ((u >> 16) & 1u)) >> 16;
  return (unsigned short)u;
}
__device__ __forceinline__ unsigned pack_bf2(float lo, float hi) {
  unsigned a = __float_as_uint(lo) + 0x8000u;
  unsigned b = __float_as_uint(hi) + 0x8000u;
  return __builtin_amdgcn_perm(b, a, 0x07060302);
}
__device__ __forceinline__ void load_lds16(const unsigned short* g, unsigned short* l) {
  __builtin_amdgcn_global_load_lds(
      (const __attribute__((address_space(1))) void*)g,
      (__attribute__((address_space(3))) void*)l, 16, 0, 0);
}

// Hazard-safe permlane swaps (gfx950), v12/v16-verified on hardware.
#if __has_builtin(__builtin_amdgcn_permlane32_swap)
__device__ __forceinline__ void pl32_swap(unsigned& a, unsigned& b) {
  uint2v r = __builtin_amdgcn_permlane32_swap(a, b, false, false);
  a = r[0]; b = r[1];
}
__device__ __forceinline__ void pl16_swap(unsigned& a, unsigned& b) {
  uint2v r = __builtin_amdgcn_permlane16_swap(a, b, false, false);
  a = r[0]; b = r[1];
}
#else
__device__ __forceinline__ void pl32_swap(unsigned& a, unsigned& b) {
  asm volatile("s_nop 1\n\tv_permlane32_swap_b32 %0, %1\n\ts_nop 1"
               : "+v"(a), "+v"(b));
}
__device__ __forceinline__ void pl16_swap(unsigned& a, unsigned& b) {
  asm volatile("s_nop 1\n\tv_permlane16_swap_b32 %0, %1\n\ts_nop 1"
               : "+v"(a), "+v"(b));
}
#endif

// --- p: fused prep ---------------------------------------------------------
__global__ __launch_bounds__(256) void prep(
    const float* __restrict__ x, unsigned short* __restrict__ x_bf,
    const float* __restrict__ W_qkv, unsigned short* __restrict__ Wqkv_t,
    const float* __restrict__ W_out, unsigned short* __restrict__ Wout_t)
{
  const int tid = threadIdx.x;
  if (blockIdx.z == 2) {
    const int bid = blockIdx.y * 48 + blockIdx.x;          // 0..767
    const int n = 4096 * 1024;
    for (int i = bid * 2048 + tid * 8; i < n; i += 768 * 2048) {
      float4 f0 = *(const float4*)(x + i);
      float4 f1 = *(const float4*)(x + i + 4);
      union { unsigned short u[8]; uint4 v; } pk;
      pk.u[0] = f2bf(f0.x); pk.u[1] = f2bf(f0.y); pk.u[2] = f2bf(f0.z); pk.u[3] = f2bf(f0.w);
      pk.u[4] = f2bf(f1.x); pk.u[5] = f2bf(f1.y); pk.u[6] = f2bf(f1.z); pk.u[7] = f2bf(f1.w);
      *(uint4*)(x_bf + i) = pk.v;
    }
    return;
  }
  const float* in = (blockIdx.z == 0) ? W_qkv : W_out;
  unsigned short* out = (blockIdx.z == 0) ? Wqkv_t : Wout_t;
  const int R = 1024;
  const int C = (blockIdx.z == 0) ? 3072 : 1024;
  const int c0 = blockIdx.x * 64;
  if (c0 >= C) return;
  __shared__ float tile[64][65];
  const int r0 = blockIdx.y * 64;
  {
    const int rr = tid >> 4;
    const int cc = (tid & 15) * 4;
#pragma unroll
    for (int it = 0; it < 4; ++it) {
      float4 f = *(const float4*)&in[(size_t)(r0 + rr + 16 * it) * C + c0 + cc];
      tile[rr + 16 * it][cc + 0] = f.x;
      tile[rr + 16 * it][cc + 1] = f.y;
      tile[rr + 16 * it][cc + 2] = f.z;
      tile[rr + 16 * it][cc + 3] = f.w;
    }
  }
  __syncthreads();
  {
    const int cr = tid >> 2;
    const int rk = (tid & 3) * 16;
    union { unsigned short u[16]; uint4 v[2]; } pk;
#pragma unroll
    for (int j = 0; j < 16; ++j) pk.u[j] = f2bf(tile[rk + j][cr]);
    uint4* dst = (uint4*)&out[(size_t)(c0 + cr) * R + r0 + rk];
    dst[0] = pk.v[0];
    dst[1] = pk.v[1];
  }
}

// --- k1/k3: GEMM C = A[M,K] @ Bt[N,K]^T + bias -----------------------------
// Tile 128 x NB, K-step BK. XOR-swizzled LDS (CPR=BK/8 chunks/row), XCD
// remap. MODE 0: f32 out (ldc = N). MODE 1: bf16: cols<1024 Q (scaled
// log2e/8), 1024..2047 K -> qk_bf; >=2048 V -> vT.
template <int MODE, int NB, int BK>
__global__ __launch_bounds__(256) void gemm_mfma(
    const unsigned short* __restrict__ A,
    const unsigned short* __restrict__ Bt,
    const float* __restrict__ bias,
    void* __restrict__ Cout, unsigned short* __restrict__ vT,
    int M, int N, int K, int ldc)
{
  constexpr int NI = NB / 32;
  constexpr int CPR = BK / 8;              // 16B chunks per row
  constexpr int RPC = 64 / CPR;            // rows staged per load call
  __shared__ unsigned short As[128][BK];
  __shared__ unsigned short Bs[NB][BK];
  const int tid = threadIdx.x;
  const int wave = tid >> 6, lane = tid & 63;
  const int l16 = lane & 15, quad = lane >> 4;

  // XCD-aware bijective block remap (nwg % 8 == 0 for both k1 and k3)
  const int bid = blockIdx.y * gridDim.x + blockIdx.x;
  const int nwg = gridDim.x * gridDim.y;
  const int sbid = (bid & 7) * (nwg >> 3) + (bid >> 3);
  const int bx = sbid % gridDim.x;
  const int by = sbid / gridDim.x;
  const int m0 = by * 128, n0 = bx * NB;

  const int wm = (wave & 1) * 64, wn = (wave >> 1) * (NB / 2);
  const int lr = lane / CPR;
  const int p  = lane % CPR;
  const int swk = l16 & (CPR - 1);         // read-side swizzle key

  f32x4 acc[4][NI] = {};

  for (int k0 = 0; k0 < K; k0 += BK) {
    __syncthreads();
#pragma unroll
    for (int i = 0; i < 32 / RPC; ++i) {   // A: 32 rows per wave
      const int rbase = wave * 32 + i * RPC;
      const int rl = rbase + lr;
      load_lds16(&A[(size_t)(m0 + rl) * K + k0 + ((p ^ (rl & (CPR - 1))) << 3)],
                 &As[rbase][0]);
    }
#pragma unroll
    for (int i = 0; i < (NB / 4) / RPC; ++i) {  // B: NB/4 rows per wave
      const int rbase = wave * (NB / 4) + i * RPC;
      const int rl = rbase + lr;
      load_lds16(&Bt[(size_t)(n0 + rl) * K + k0 + ((p ^ (rl & (CPR - 1))) << 3)],
                 &Bs[rbase][0]);
    }
    __syncthreads();

#pragma unroll
    for (int kk = 0; kk < BK / 32; ++kk) {
      bf16x8 af[4], bfr[NI];
#pragma unroll
      for (int mi = 0; mi < 4; ++mi)
        af[mi] = *(const bf16x8*)&As[wm + 16 * mi + l16][(((kk << 2) + quad) ^ swk) * 8];
#pragma unroll
      for (int ni = 0; ni < NI; ++ni)
        bfr[ni] = *(const bf16x8*)&Bs[wn + 16 * ni + l16][(((kk << 2) + quad) ^ swk) * 8];
#pragma unroll
      for (int mi = 0; mi < 4; ++mi)
#pragma unroll
        for (int ni = 0; ni < NI; ++ni)
          acc[mi][ni] = __builtin_amdgcn_mfma_f32_16x16x32_bf16(
              af[mi], bfr[ni], acc[mi][ni], 0, 0, 0);
    }
  }

  const float SCQ = 0.18033688f;   // log2(e)/sqrt(64), folded into Q
#pragma unroll
  for (int ni = 0; ni < NI; ++ni) {
    const int colb = n0 + wn + 16 * ni;
    const int col = colb + l16;
    const float bv = bias[col];
    if (MODE == 0) {
#pragma unroll
      for (int mi = 0; mi < 4; ++mi)
#pragma unroll
        for (int i = 0; i < 4; ++i) {
          const int row = m0 + wm + 16 * mi + quad * 4 + i;
          ((float*)Cout)[(size_t)row * ldc + col] = acc[mi][ni][i] + bv;
        }
    } else if (colb < 1024) {          // Q: pre-scale for exp2 softmax
#pragma unroll
      for (int mi = 0; mi < 4; ++mi)
#pragma unroll
        for (int i = 0; i < 4; ++i) {
          const int row = m0 + wm + 16 * mi + quad * 4 + i;
          ((unsigned short*)Cout)[(size_t)row * ldc + col] = f2bf((acc[mi][ni][i] + bv) * SCQ);
        }
    } else if (colb < 2048) {          // K
#pragma unroll
      for (int mi = 0; mi < 4; ++mi)
#pragma unroll
        for (int i = 0; i < 4; ++i) {
          const int row = m0 + wm + 16 * mi + quad * 4 + i;
          ((unsigned short*)Cout)[(size_t)row * ldc + col] = f2bf(acc[mi][ni][i] + bv);
        }
    } else {                           // V -> vT[bh][d][t], packed pairs in t
      const int h = (col - 2048) >> 6, d = col & 63;
#pragma unroll
      for (int mi = 0; mi < 4; ++mi) {
        const int row = m0 + wm + 16 * mi + quad * 4;   // +i, i=0..3
        const int bb = row >> 11, t = row & 2047;
        unsigned short* dst = &vT[((size_t)(bb * 16 + h) * 64 + d) * 2048 + t];
        *(unsigned*)(dst)     = pack_bf2(acc[mi][ni][0] + bv, acc[mi][ni][1] + bv);
        *(unsigned*)(dst + 2) = pack_bf2(acc[mi][ni][2] + bv, acc[mi][ni][3] + bv);
      }
    }
  }
}

// --- k2: flash attention, KVBLK=128 + XCD remap ----------------------------
// Block = 4 waves; wave w: q rows [bx*128 + 32w, +32), all 2048 keys.
// Ks/Vs[buf][sub][4096]: 64KB. Iteration it processes sub-tiles 2it, 2it+1
// from buf[it&1], stages 2it+2/2it+3 into buf[it&1^1], prefetches
// 2it+4/2it+5 into regs. ONE barrier per 128 keys. XCD remap: chunked
// assignment puts each bh-group (16 q-tile blocks sharing a 512KB K/V
// panel) on one XCD -> panel fetched into one L2 (was ~3x over-fetch).
__global__ __launch_bounds__(256, 2) void attn_mfma(
    const unsigned short* __restrict__ qk,    // [4096][2048] (Q|K)
    const unsigned short* __restrict__ vT,    // [32][64][2048]
    unsigned short* __restrict__ attn_out)    // [4096][1024]
{
  __shared__ unsigned short Ks[2][2][4096];
  __shared__ unsigned short Vs[2][2][4096];

  const int tid = threadIdx.x;
  const int wave = tid >> 6, lane = tid & 63;
  const int l16 = lane & 15, quad = lane >> 4;

  // XCD-aware bijective block remap (nwg = 512, 512 % 8 == 0)
  const int bid0 = blockIdx.y * gridDim.x + blockIdx.x;
  const int nwg = gridDim.x * gridDim.y;
  const int sbid = (bid0 & 7) * (nwg >> 3) + (bid0 >> 3);
  const int bx = sbid % gridDim.x;              // q-tile index
  const int bh = sbid / gridDim.x;              // head index
  const int b = bh >> 4, h = bh & 15;
  const int s0 = bx * 128 + wave * 32;

  const unsigned short* qb = qk + (size_t)(b * 2048) * 2048 + h * 64;
  const unsigned short* kb = qb + 1024;
  const unsigned short* vb = vT + (size_t)bh * 64 * 2048;

  // staging geometry (16B per lane, swizzled chunks) -- per 64-key sub-tile
  const int srow = lane >> 3;                     // 0..7
  const int schunk = ((lane & 7) ^ srow) * 8;     // swizzled 16B chunk
  const int r0a = wave * 16;
  const unsigned short* kg0 = kb + (size_t)(r0a + srow) * 2048 + schunk;
  const unsigned short* kg1 = kg0 + (size_t)8 * 2048;
  const unsigned short* vg0 = vb + (size_t)(r0a + srow) * 2048 + schunk;
  const unsigned short* vg1 = vg0 + (size_t)8 * 2048;
  const int wd0 = r0a * 64 + lane * 8;            // LDS dst (shorts)
  const int wd1 = (r0a + 8) * 64 + lane * 8;

  // prologue: tiles 0,1 -> buf0 sub0/1; tiles 2,3 -> regs (in flight)
  uint4 kr0 = *(const uint4*)(kg0);
  uint4 kr1 = *(const uint4*)(kg1);
  uint4 vr0 = *(const uint4*)(vg0);
  uint4 vr1 = *(const uint4*)(vg1);
  *(uint4*)&Ks[0][0][wd0] = kr0;  *(uint4*)&Ks[0][0][wd1] = kr1;
  *(uint4*)&Vs[0][0][wd0] = vr0;  *(uint4*)&Vs[0][0][wd1] = vr1;
  kr0 = *(const uint4*)(kg0 + (size_t)64 * 2048);
  kr1 = *(const uint4*)(kg1 + (size_t)64 * 2048);
  vr0 = *(const uint4*)(vg0 + 64);
  vr1 = *(const uint4*)(vg1 + 64);
  *(uint4*)&Ks[0][1][wd0] = kr0;  *(uint4*)&Ks[0][1][wd1] = kr1;
  *(uint4*)&Vs[0][1][wd0] = vr0;  *(uint4*)&Vs[0][1][wd1] = vr1;
  kr0 = *(const uint4*)(kg0 + (size_t)2 * 64 * 2048);
  kr1 = *(const uint4*)(kg1 + (size_t)2 * 64 * 2048);
  vr0 = *(const uint4*)(vg0 + 128);
  vr1 = *(const uint4*)(vg1 + 128);
  uint4 kr2 = *(const uint4*)(kg0 + (size_t)3 * 64 * 2048);
  uint4 kr3 = *(const uint4*)(kg1 + (size_t)3 * 64 * 2048);
  uint4 vr2 = *(const uint4*)(vg0 + 192);
  uint4 vr3 = *(const uint4*)(vg1 + 192);

  // Q frags (x32 B-layout: k=d, n=q); Q pre-scaled by log2e/8
  bf16x8 qf[2][2];
#pragma unroll
  for (int mt = 0; mt < 2; ++mt)
#pragma unroll
    for (int ks = 0; ks < 2; ++ks)
      qf[mt][ks] = *(const bf16x8*)&qb[(size_t)(s0 + 16 * mt + l16) * 2048 + 32 * ks + quad * 8];

  f32x4 O[2][4] = {};      // O^T accum: [mt][nd], C col=q=l16, row=d local
  f32x4 lacc[2] = {};      // l via ones-MFMA (rows replicated)
  const bf16x8 ones8 = {(short)0x3F80, (short)0x3F80, (short)0x3F80, (short)0x3F80,
                        (short)0x3F80, (short)0x3F80, (short)0x3F80, (short)0x3F80};
  const int sw = l16 & 7;

  __syncthreads();

  for (int it = 0; it < 16; ++it) {
    const int cur = it & 1;

#pragma unroll
    for (int s = 0; s < 2; ++s) {
      // ---- K frags (x32 A-layout: m=t, k=d) from swizzled LDS ----
      bf16x8 kf[4][2];
#pragma unroll
      for (int nt = 0; nt < 4; ++nt) {
        const int rb = (16 * nt + l16) * 64;
        kf[nt][0] = *(const bf16x8*)&Ks[cur][s][rb + ((quad ^ sw) * 8)];
        kf[nt][1] = *(const bf16x8*)&Ks[cur][s][rb + (((4 + quad) ^ sw) * 8)];
      }

      // ---- S^T = K Q^T (x32): C row=t=quad*4+i, col=q=l16 ----
      f32x4 sf[4][2];
#pragma unroll
      for (int nt = 0; nt < 4; ++nt)
#pragma unroll
        for (int mt = 0; mt < 2; ++mt) {
          f32x4 c = {0.0f, 0.0f, 0.0f, 0.0f};
          c = __builtin_amdgcn_mfma_f32_16x16x32_bf16(kf[nt][0], qf[mt][0], c, 0, 0, 0);
          c = __builtin_amdgcn_mfma_f32_16x16x32_bf16(kf[nt][1], qf[mt][1], c, 0, 0, 0);
          sf[nt][mt] = c;
        }

      // ---- stage tile 2it+2+s (regs -> buf[cur^1][s]); prefetch 2it+4+s --
      if (it < 15) {
        if (s == 0) {
          *(uint4*)&Ks[cur ^ 1][0][wd0] = kr0;
          *(uint4*)&Ks[cur ^ 1][0][wd1] = kr1;
          *(uint4*)&Vs[cur ^ 1][0][wd0] = vr0;
          *(uint4*)&Vs[cur ^ 1][0][wd1] = vr1;
          if (it < 14) {
            const size_t ko = (size_t)(2 * it + 4) * 64 * 2048;
            kr0 = *(const uint4*)(kg0 + ko);
            kr1 = *(const uint4*)(kg1 + ko);
            vr0 = *(const uint4*)(vg0 + (2 * it + 4) * 64);
            vr1 = *(const uint4*)(vg1 + (2 * it + 4) * 64);
          }
        } else {
          *(uint4*)&Ks[cur ^ 1][1][wd0] = kr2;
          *(uint4*)&Ks[cur ^ 1][1][wd1] = kr3;
          *(uint4*)&Vs[cur ^ 1][1][wd0] = vr2;
          *(uint4*)&Vs[cur ^ 1][1][wd1] = vr3;
          if (it < 14) {
            const size_t ko = (size_t)(2 * it + 5) * 64 * 2048;
            kr2 = *(const uint4*)(kg0 + ko);
            kr3 = *(const uint4*)(kg1 + ko);
            vr2 = *(const uint4*)(vg0 + (2 * it + 5) * 64);
            vr3 = *(const uint4*)(vg1 + (2 * it + 5) * 64);
          }
        }
      }

      // ---- V frags (x32 A-layout: m=d, k=t): same swizzle as K ----
      bf16x8 vf[4][2];
#pragma unroll
      for (int nd = 0; nd < 4; ++nd) {
        const int rb = (16 * nd + l16) * 64;
        vf[nd][0] = *(const bf16x8*)&Vs[cur][s][rb + ((quad ^ sw) * 8)];
        vf[nd][1] = *(const bf16x8*)&Vs[cur][s][rb + (((4 + quad) ^ sw) * 8)];
      }

      // ---- p = exp2(s); pack_bf2; permlane-redistribute to x32 B-frags --
      bf16x8 pB[2][2];   // [mt][c]
#pragma unroll
      for (int mt = 0; mt < 2; ++mt)
#pragma unroll
        for (int c = 0; c < 2; ++c) {
          const f32x4 sa = sf[2 * c][mt];
          const f32x4 sb = sf[2 * c + 1][mt];
          unsigned X = pack_bf2(__builtin_amdgcn_exp2f(sa[0]), __builtin_amdgcn_exp2f(sa[1]));
          unsigned Y = pack_bf2(__builtin_amdgcn_exp2f(sa[2]), __builtin_amdgcn_exp2f(sa[3]));
          unsigned Z = pack_bf2(__builtin_amdgcn_exp2f(sb[0]), __builtin_amdgcn_exp2f(sb[1]));
          unsigned W = pack_bf2(__builtin_amdgcn_exp2f(sb[2]), __builtin_amdgcn_exp2f(sb[3]));
          pl32_swap(X, Z);
          pl16_swap(X, Z);
          pl32_swap(Y, W);
          pl16_swap(Y, W);
          union { unsigned u[4]; bf16x8 v; } pk;
          pk.u[0] = X; pk.u[1] = Y; pk.u[2] = Z; pk.u[3] = W;
          pB[mt][c] = pk.v;
        }

      // ---- O^T += V^T P^T (x32); l += ones P^T (x32) ----
#pragma unroll
      for (int c = 0; c < 2; ++c)
#pragma unroll
        for (int mt = 0; mt < 2; ++mt) {
          lacc[mt] = MFMA32(ones8, pB[mt][c], lacc[mt]);
#pragma unroll
          for (int nd = 0; nd < 4; ++nd)
            O[mt][nd] = MFMA32(vf[nd][c], pB[mt][c], O[mt][nd]);
        }
    }

    __syncthreads();
  }

  // ---- epilogue: lane holds q=s0+16mt+l16, d=16nd+quad*4+{0..3} ----
#pragma unroll
  for (int mt = 0; mt < 2; ++mt) {
    const float inv = 1.0f / lacc[mt][0];
    const size_t row = (size_t)(b * 2048 + s0 + 16 * mt + l16);
#pragma unroll
    for (int nd = 0; nd < 4; ++nd) {
      uint2 w;
      w.x = pack_bf2(O[mt][nd][0] * inv, O[mt][nd][1] * inv);
      w.y = pack_bf2(O[mt][nd][2] * inv, O[mt][nd][3] * inv);
      *(uint2*)&attn_out[row * 1024 + h * 64 + 16 * nd + quad * 4] = w;
    }
  }
}

extern "C" void kernel_launch(void* const* d_in, const int* in_sizes, int n_in,
                              void* d_out, int out_size, void* d_ws, size_t ws_size,
                              hipStream_t stream) {
  const float* x     = (const float*)d_in[0];
  const float* W_qkv = (const float*)d_in[1];
  const float* b_qkv = (const float*)d_in[2];
  const float* W_out = (const float*)d_in[3];
  const float* b_out = (const float*)d_in[4];
  float* out = (float*)d_out;

  char* ws = (char*)d_ws;
  const size_t MB = 1048576;
  unsigned short* Wout_t = (unsigned short*)(ws);             //  0-2 MB
  unsigned short* qk_bf  = (unsigned short*)(ws + 2 * MB);    //  2-18 MB
  unsigned short* vT     = (unsigned short*)(ws + 18 * MB);   // 18-26 MB
  unsigned short* attn_b = (unsigned short*)(ws + 26 * MB);   // 26-34 MB
  unsigned short* x_bf   = (unsigned short*)(ws + 34 * MB);   // 34-42 MB
  unsigned short* Wqkv_t = (unsigned short*)(ws + 42 * MB);   // 42-48 MB

  prep<<<dim3(48, 16, 3), 256, 0, stream>>>(x, x_bf, W_qkv, Wqkv_t, W_out, Wout_t);

  gemm_mfma<1, 192, 64><<<dim3(16, 32), 256, 0, stream>>>(x_bf, Wqkv_t, b_qkv, qk_bf, vT,
                                                          4096, 3072, 1024, 2048);
  attn_mfma<<<dim3(16, 32), 256, 0, stream>>>(qk_bf, vT, attn_b);
  gemm_mfma<0, 64, 64><<<dim3(16, 32), 256, 0, stream>>>(attn_b, Wout_t, b_out, out, nullptr,
                                                         4096, 1024, 1024, 1024);
}